// Round 9
// baseline (101.208 us; speedup 1.0000x reference)
//
#include <hip/hip_runtime.h>
#include <hip/hip_bf16.h>
#include <hip/hip_fp16.h>

// ---- problem constants -----------------------------------------------------
#define ZZ      87
#define NREF    7
#define NC      5
#define NW      23
#define NATOMS  75000
#define NPAIRS  1500000
#define IAW     (ZZ*NREF*NW)        // 14007 alpha elements

// ---- sort params ------------------------------------------------------------
#define BSH     7                   // bucket = i >> 7
#define BSZ     128                 // atoms per bucket
#define NB      586                 // ceil(NATOMS/BSZ)
#define BLKP    4096                // pairs per hist/scatter block
#define NBLK    367                 // ceil(NPAIRS/BLKP)
#define PREPB   74                  // ceil(75264/1024) prep blocks inside scan kernel
#define PACK_BLKS 22                // ceil(11050/512)

// ---- workspace layout (float offsets) ---------------------------------------
// [0..4] scalars: spq, s6, s8, a1, a2 ; ws[8] (int) = scan done-counter
#define OFF_DONE    8
#define OFF_ALPHA   32              // 14007 (alpha * sqrt(cpw*3/2pi), fp32)
#define OFF_AD      14040           // float2[NATOMS]: (rcov[sp], en[sp])
#define OFF_NCOORD  164040          // 75000 (fallback path only)
#define OFF_ENERGY  239040          // 75000 (fallback accumulator)
#define OFF_IMG     OFF_ENERGY      // sorted path: 14356-dword LDS image lives here
#define OFF_BETA    314048          // half[NATOMS*24] (48B rows, 16B aligned)
#define OFF_HIST    1214048         // int[NBLK*NB] (transposed [blk][b])
#define OFF_BTOT    1643586         // int[NB] (+pad)
#define OFF_BBASE   1644176         // int[NB+1] (+pad)
#define OFF_REC     1644768         // uint2[NPAIRS] (8B aligned: even offset)
#define SORT_WS_NEED      ((size_t)(OFF_REC + 2*NPAIRS) * 4)   // ~17.7 MiB

// ---- LDS image layout (dword offsets inside image) ---------------------------
#define IMG_A   0       // uint[7308]: half2-packed alpha' [87][7][12] (w pairs)
#define IMG_C   7308    // float2[3045]: {cn, wght (masked: <0 if mask==0)}
#define IMG_Q   13398   // float[609]: qref = zeff + refq*spq
#define IMG_G   14008   // float4[87]: {zeff, gam, sqrt_r4r2, 0} (dword 14007 pad)
#define IMG_DW  14356   // = 4*3589, 57.4 KB

static constexpr float INV_BOHR  = (float)(1.0/0.5291772105638411);
static constexpr float HALF_HART = (float)(0.5*27.211386024367243);
static constexpr float CK4 = 4.10451f;
static constexpr float CK5 = 19.08857f;
static constexpr float INV_K6 = (float)(1.0/254.5553148552);
static constexpr float CKK = 7.5f;
static constexpr float E3F = 20.085536923187668f;       // e^3
static constexpr float C32PI = 0.47746482927568606f;    // 3/(2*pi)

// ---- dtype hedge: detect bf16 vs fp32 float tensors from s6_raw bits --------
__device__ __forceinline__ bool detect_bf16(const void* s6raw) {
    return ((*(const unsigned short*)s6raw) >> 8) == 0x3Fu;
}
__device__ __forceinline__ float ldf(const void* p, int i, bool bf) {
    if (bf) {
        unsigned int u = ((const unsigned short*)p)[i];
        return __uint_as_float(u << 16);
    }
    return ((const float*)p)[i];
}
__device__ __forceinline__ float splus(float x) {
    return (x > 15.f) ? x : log1pf(expf(x));
}
__device__ __forceinline__ void up2(unsigned int u, float* d) {
    __half2 h;
    *reinterpret_cast<unsigned int*>(&h) = u;
    float2 f = __half22float2(h);
    d[0] = f.x; d[1] = f.y;
}
__device__ __forceinline__ void unpack24(uint4 a, uint4 b, uint4 c, float* v) {
    up2(a.x, v+0);  up2(a.y, v+2);  up2(a.z, v+4);  up2(a.w, v+6);
    up2(b.x, v+8);  up2(b.y, v+10); up2(b.z, v+12); up2(b.w, v+14);
    up2(c.x, v+16); up2(c.y, v+18); up2(c.z, v+20); up2(c.w, v+22);
}
// 8 consecutive float loads starting at p0 (p0 % 8 == 0)
__device__ __forceinline__ void ld8(const void* p, int p0, bool bf, float* L) {
    if (bf) {
        uint4 u = *(const uint4*)((const unsigned short*)p + p0);
        unsigned vs[4] = {u.x, u.y, u.z, u.w};
        #pragma unroll
        for (int k = 0; k < 4; ++k) {
            L[2*k]   = __uint_as_float(vs[k] << 16);
            L[2*k+1] = __uint_as_float(vs[k] & 0xFFFF0000u);
        }
    } else {
        float4 f0 = *(const float4*)((const float*)p + p0);
        float4 f1 = *(const float4*)((const float*)p + p0 + 4);
        L[0]=f0.x; L[1]=f0.y; L[2]=f0.z; L[3]=f0.w;
        L[4]=f1.x; L[5]=f1.y; L[6]=f1.z; L[7]=f1.w;
    }
}

// ---- shared prep body (t over [0, 75776)) ------------------------------------
__device__ __forceinline__ void prep_body(int t, bool bf,
        const int* __restrict__ refsys, const int* __restrict__ species,
        const void* zeff, const void* refh, const void* sscale,
        const void* secaiw, const void* gam, const void* ascale,
        const void* alphaiw, const void* hcount, const void* cpw,
        const void* rcov, const void* en,
        const void* s6r, const void* s8r, const void* a1r,
        const void* a2r, const void* sqr, float* __restrict__ ws) {
    if (t == 0) {
        ws[0] = splus(ldf(sqr, 0, bf));
        ws[1] = splus(ldf(s6r, 0, bf));
        ws[2] = splus(ldf(s8r, 0, bf));
        ws[3] = splus(ldf(a1r, 0, bf));
        ws[4] = splus(ldf(a2r, 0, bf));
    }
    if (t < NATOMS) {
        int sp = species[t];
        ((float2*)(ws + OFF_AD))[t] = make_float2(ldf(rcov, sp, bf), ldf(en, sp, bf));
    }
    if (t >= IAW) return;
    int w  = t % NW;
    int ia = t / NW;
    int rs = refsys[ia];
    float spq  = splus(ldf(sqr, 0, bf));
    float ze   = ldf(zeff, rs, bf);
    float qmod = ze + ldf(refh, ia, bf) * spq;
    float zfac;
    if (qmod > 1e-8f) {
        float g = ldf(gam, rs, bf);
        zfac = expf(3.f * (1.f - expf(2.f * g * (1.f - ze / qmod))));
    } else {
        zfac = E3F;
    }
    float sec = ldf(sscale, rs, bf) * ldf(secaiw, rs*NW + w, bf) * zfac;
    float al  = ldf(ascale, ia, bf) *
                (ldf(alphaiw, ia*NW + w, bf) - ldf(hcount, ia, bf) * sec);
    float bsw = sqrtf(C32PI * ldf(cpw, w, bf));
    ws[OFF_ALPHA + t] = fmaxf(al, 0.f) * bsw;     // fold sqrt(c_w*3/2pi) here
}

// =================== SORTED PATH (no global atomics in hot loops) =============

// ---- K1: per-block bucket histograms (hist transposed: [blk][b]) -------------
__global__ __launch_bounds__(512) void k_hist(const int* __restrict__ eidx,
                                              int* __restrict__ hist,
                                              float* __restrict__ ws) {
    __shared__ int h[NB];
    int blk = blockIdx.x;
    if (blk == 0 && threadIdx.x == 0) ((int*)ws)[OFF_DONE] = 0;  // reset scan ticket
    for (int t = threadIdx.x; t < NB; t += 512) h[t] = 0;
    __syncthreads();
    int p0 = blk * BLKP + (int)threadIdx.x * 8;
    if (p0 + 8 <= NPAIRS) {                           // NPAIRS % 8 == 0
        int4 a0 = *(const int4*)(eidx + p0);
        int4 a1 = *(const int4*)(eidx + p0 + 4);
        atomicAdd(&h[a0.x >> BSH], 1);
        atomicAdd(&h[a0.y >> BSH], 1);
        atomicAdd(&h[a0.z >> BSH], 1);
        atomicAdd(&h[a0.w >> BSH], 1);
        atomicAdd(&h[a1.x >> BSH], 1);
        atomicAdd(&h[a1.y >> BSH], 1);
        atomicAdd(&h[a1.z >> BSH], 1);
        atomicAdd(&h[a1.w >> BSH], 1);
    }
    __syncthreads();
    for (int t = threadIdx.x; t < NB; t += 512)
        hist[(size_t)blk * NB + t] = h[t];            // coalesced row write
}

// ---- K2: per-bucket scan (blocks [0,586)) + base scan (last block) +
//          prep (blocks [586, 586+74)) -----------------------------------------
__global__ __launch_bounds__(1024) void k_scan_prep(
        int* __restrict__ hist, int* __restrict__ btot, int* __restrict__ bbase,
        const int* __restrict__ refsys, const int* __restrict__ species,
        const void* zeff, const void* refh, const void* sscale,
        const void* secaiw, const void* gam, const void* ascale,
        const void* alphaiw, const void* hcount, const void* cpw,
        const void* rcov, const void* en,
        const void* s6r, const void* s8r, const void* a1r,
        const void* a2r, const void* sqr,
        float* __restrict__ ws) {
    const bool bf = detect_bf16(s6r);
    int blk = blockIdx.x;
    if (blk >= NB) {                                  // ---- prep part ----
        prep_body((blk - NB) * 1024 + (int)threadIdx.x, bf, refsys, species,
                  zeff, refh, sscale, secaiw, gam, ascale, alphaiw, hcount,
                  cpw, rcov, en, s6r, s8r, a1r, a2r, sqr, ws);
        return;
    }
    // ---- per-bucket exclusive scan over NBLK block entries ----
    int b = blk;
    int t = threadIdx.x;
    __shared__ int wsum[16];
    __shared__ int sTicket;
    int v = (t < NBLK) ? hist[(size_t)t * NB + b] : 0;
    int lane = t & 63, wid = t >> 6;
    int x = v;
    #pragma unroll
    for (int d = 1; d < 64; d <<= 1) {
        int n = __shfl_up(x, d, 64);
        if (lane >= d) x += n;
    }
    if (lane == 63) wsum[wid] = x;
    __syncthreads();
    if (t == 0) {
        int acc = 0;
        #pragma unroll
        for (int w = 0; w < 16; ++w) { int s = wsum[w]; wsum[w] = acc; acc += s; }
    }
    __syncthreads();
    int incl = x + wsum[wid];
    if (t < NBLK) hist[(size_t)t * NB + b] = incl - v;   // exclusive
    if (t == 1023) {
        btot[b] = incl;                                   // bucket total
        __threadfence();                                  // publish before ticket
        sTicket = atomicAdd((int*)ws + OFF_DONE, 1);
    }
    __syncthreads();
    if (sTicket != NB - 1) return;
    // ---- last-finishing block: scan bucket totals -> bases ----
    __threadfence();
    int v2 = (t < NB) ? atomicAdd(&btot[t], 0) : 0;       // coherent read
    int x2 = v2;
    #pragma unroll
    for (int d = 1; d < 64; d <<= 1) {
        int n = __shfl_up(x2, d, 64);
        if (lane >= d) x2 += n;
    }
    if (lane == 63) wsum[wid] = x2;
    __syncthreads();
    if (t == 0) {
        int acc = 0;
        #pragma unroll
        for (int w = 0; w < 16; ++w) { int s = wsum[w]; wsum[w] = acc; acc += s; }
    }
    __syncthreads();
    int incl2 = x2 + wsum[wid];
    if (t < NB) bbase[t] = incl2 - v2;
    if (t == 1023) bbase[NB] = incl2;                     // = NPAIRS
}

// ---- K3: scatter (blocks [0,367)) + pack image (blocks [367,367+22)) ---------
__global__ __launch_bounds__(512) void k_scatter_pack(
        const int* __restrict__ eidx, const void* lengths, const void* s6r,
        const int* __restrict__ hist, const int* __restrict__ bbase,
        uint2* __restrict__ rec,
        const void* zeff, const void* gam, const void* mask,
        const void* wght, const void* cn, const void* refq, const void* sq4,
        float* __restrict__ ws) {
    const bool bf = detect_bf16(s6r);
    __shared__ int cnt[NB];
    int blk = blockIdx.x;
    if (blk >= NBLK) {                                // ---- pack part ----
        unsigned* img = (unsigned*)(ws + OFF_IMG);
        int t = (blk - NBLK) * 512 + (int)threadIdx.x;
        if (t < 7308) {                               // alpha' half2 pack
            int row = t / 12, u = t % 12;
            int w0 = 2*u, w1 = 2*u + 1;
            const float* aF = ws + OFF_ALPHA + row * NW;
            float v0 = aF[w0];
            float v1 = (w1 < NW) ? aF[w1] : 0.f;
            unsigned lo = __half_as_ushort(__float2half(v0));
            unsigned hi = __half_as_ushort(__float2half(v1));
            img[t] = lo | (hi << 16);
        } else if (t < 7308 + 3045) {                 // {cn, masked wght}
            int e = t - 7308;                         // e = sp*35 + a*5 + c
            float cnv = ldf(cn, e, bf);
            float wv  = (ldf(mask, e, bf) > 0.5f) ? ldf(wght, e, bf) : -1.f;
            ((float2*)(img + IMG_C))[e] = make_float2(cnv, wv);
        } else if (t < 10353 + 609) {                 // qref = zeff + refq*spq
            int e = t - 10353;                        // e = sp*7 + a
            int sp = e / NREF;
            ((float*)(img + IMG_Q))[e] = ldf(zeff, sp, bf) + ldf(refq, e, bf) * ws[0];
        } else if (t < 10962 + 87) {                  // {zeff, gam, sq4, 0}
            int sp = t - 10962;
            ((float4*)(img + IMG_G))[sp] = make_float4(ldf(zeff, sp, bf),
                                                       ldf(gam, sp, bf),
                                                       ldf(sq4, sp, bf), 0.f);
        } else if (t == 11049) {
            img[14007] = 0;                           // alignment pad
        }
        return;
    }
    // ---- scatter part ----
    const int* hcol = hist + (size_t)blk * NB;        // coalesced row read
    for (int t = threadIdx.x; t < NB; t += 512)
        cnt[t] = bbase[t] + hcol[t];                  // absolute write cursor
    __syncthreads();
    int p0 = blk * BLKP + (int)threadIdx.x * 8;
    if (p0 + 8 > NPAIRS) return;                      // NPAIRS % 8 == 0
    int4 a0 = *(const int4*)(eidx + p0);
    int4 a1 = *(const int4*)(eidx + p0 + 4);
    int4 b0 = *(const int4*)(eidx + NPAIRS + p0);
    int4 b1 = *(const int4*)(eidx + NPAIRS + p0 + 4);
    float L[8];
    ld8(lengths, p0, bf, L);
    int is[8] = {a0.x,a0.y,a0.z,a0.w,a1.x,a1.y,a1.z,a1.w};
    int js[8] = {b0.x,b0.y,b0.z,b0.w,b1.x,b1.y,b1.z,b1.w};
    #pragma unroll
    for (int k = 0; k < 8; ++k) {
        int b = is[k] >> BSH;
        int pos = atomicAdd(&cnt[b], 1);              // LDS atomic -> final pos
        rec[pos] = make_uint2(((unsigned)(is[k] & (BSZ-1)) << 17) | (unsigned)js[k],
                              __float_as_uint(L[k]));
    }
}

// ---- K4: ncoord + beta fused (one block per bucket; ncoord stays in LDS) -----
__global__ __launch_bounds__(512) void k_ncbeta(const uint2* __restrict__ rec,
        const int* __restrict__ bbase, const int* __restrict__ species,
        const void* pq, const void* s6r, float* __restrict__ ws) {
    const bool bf = detect_bf16(s6r);
    __shared__ __align__(16) unsigned s_img[IMG_DW];
    __shared__ float bins[BSZ];
    __shared__ float adl[BSZ * 2];
    int b = blockIdx.x;
    int a0 = b << BSH;
    int na = NATOMS - a0; if (na > BSZ) na = BSZ;
    {   // cooperative image fill (3589 uint4, coalesced, L2-resident)
        const uint4* g4 = (const uint4*)(ws + OFF_IMG);
        uint4* s4 = (uint4*)s_img;
        for (int t = threadIdx.x; t < IMG_DW/4; t += 512) s4[t] = g4[t];
    }
    for (int t = threadIdx.x; t < BSZ; t += 512) bins[t] = 0.f;
    const float2* AD = (const float2*)(ws + OFF_AD);
    for (int t = threadIdx.x; t < na; t += 512) {
        float2 v = AD[a0 + t];
        adl[2*t] = v.x; adl[2*t + 1] = v.y;
    }
    __syncthreads();
    // ---- ncoord pair sweep ----
    int bs = bbase[b], be = bbase[b + 1];
    for (int p = bs + (int)threadIdx.x; p < be; p += 2*512) {
        int p2 = p + 512;
        bool h2 = (p2 < be);
        uint2 r1 = rec[p];
        uint2 r2 = h2 ? rec[p2] : r1;
        int il1 = (r1.x >> 17) & (BSZ-1), j1 = r1.x & 0x1FFFF;
        int il2 = (r2.x >> 17) & (BSZ-1), j2 = r2.x & 0x1FFFF;
        float2 aj1 = AD[j1];
        float2 aj2 = AD[j2];
        {
            float r  = __uint_as_float(r1.y) * INV_BOHR;
            float rc = (4.f/3.f) * (adl[2*il1] + aj1.x);
            float d  = fabsf(adl[2*il1+1] - aj1.y) + CK5;
            float cf = CK4 * expf(-(d*d)*INV_K6) * 0.5f * (1.f + erff(-CKK*(r-rc)/rc));
            atomicAdd(&bins[il1], cf);
        }
        if (h2) {
            float r  = __uint_as_float(r2.y) * INV_BOHR;
            float rc = (4.f/3.f) * (adl[2*il2] + aj2.x);
            float d  = fabsf(adl[2*il2+1] - aj2.y) + CK5;
            float cf = CK4 * expf(-(d*d)*INV_K6) * 0.5f * (1.f + erff(-CKK*(r-rc)/rc));
            atomicAdd(&bins[il2], cf);
        }
    }
    __syncthreads();
    // ---- beta for this bucket's atoms (t < na) ----
    int t = threadIdx.x;
    if (t >= na) return;
    int k = a0 + t;
    const unsigned* sA = s_img;                          // alpha' half2
    const float2*   sC = (const float2*)(s_img + IMG_C); // {cn, masked wght}
    const float*    sQ = (const float*)(s_img + IMG_Q);  // qref
    const float4*   sG = (const float4*)(s_img + IMG_G); // {zeff, gam, sq4}

    int sp = species[k];
    float nce = bins[t];
    float4 zg = sG[sp];
    float qmod = zg.x + ldf(pq, k, bf);

    float gw[NREF];
    float sum = 0.f;
    #pragma unroll
    for (int a = 0; a < NREF; ++a) {
        float g = 0.f;
        #pragma unroll
        for (int c = 0; c < NC; ++c) {
            float2 cw = sC[sp*35 + a*NC + c];
            float dlt = nce - cw.x;
            float e = __expf(-6.f * cw.y * dlt * dlt);
            g += (cw.y > 0.f) ? e : 0.f;                 // mask folded into sign
        }
        gw[a] = g; sum += g;
    }
    float inv = 1.f / fmaxf(sum, 1e-7f);                 // fixgweights dead code

    float2 acc[12];
    #pragma unroll
    for (int u = 0; u < 12; ++u) acc[u] = make_float2(0.f, 0.f);
    #pragma unroll
    for (int a = 0; a < NREF; ++a) {
        float qref = sQ[sp*NREF + a];
        float zf = (qmod > 1e-8f)
                 ? __expf(3.f * (1.f - __expf(2.f * zg.y * (1.f - qref / qmod))))
                 : E3F;
        float za = zf * gw[a] * inv;
        const uint2* ar = (const uint2*)(sA + (sp*NREF + a) * 12);
        #pragma unroll
        for (int u2 = 0; u2 < 6; ++u2) {
            uint2 h = ar[u2];
            float f[4];
            up2(h.x, f); up2(h.y, f+2);
            acc[2*u2].x   = fmaf(f[0], za, acc[2*u2].x);
            acc[2*u2].y   = fmaf(f[1], za, acc[2*u2].y);
            acc[2*u2+1].x = fmaf(f[2], za, acc[2*u2+1].x);
            acc[2*u2+1].y = fmaf(f[3], za, acc[2*u2+1].y);
        }
    }
    alignas(16) __half hrow[24];
    #pragma unroll
    for (int u = 0; u < 12; ++u) {
        hrow[2*u]   = __float2half(acc[u].x);
        hrow[2*u+1] = __float2half(acc[u].y);
    }
    hrow[23] = __float2half(zg.z);                       // sqrt_r4r2[sp]
    uint4* dst = (uint4*)((char*)(ws + OFF_BETA) + (size_t)k * 48);
    const uint4* src = (const uint4*)hrow;
    dst[0] = src[0]; dst[1] = src[1]; dst[2] = src[2];
}

// ---- pair energy -------------------------------------------------------------
__device__ __forceinline__ float pair_energy(const float* vi, const float* vj,
                                             float len, float s6, float s8,
                                             float a1, float a2) {
    float c6 = 0.f;
    #pragma unroll
    for (int w = 0; w < NW; ++w) c6 = fmaf(vi[w], vj[w], c6);
    float rr = 3.f * vi[23] * vj[23];
    float r  = len * INV_BOHR;
    float r2 = r * r;
    float r6 = r2 * r2 * r2;
    float r8 = r6 * r2;
    float r0   = a1 * sqrtf(rr) + a2;
    float r0sq = r0 * r0;
    float r0_6 = r0sq * r0sq * r0sq;
    float r0_8 = r0_6 * r0sq;
    return -c6 * (s6 / (r6 + r0_6) + s8 * rr / (r8 + r0_8));
}

// ---- K5: energy via LDS bins, fused finalize (one block per bucket) ----------
__global__ __launch_bounds__(512) void k_energy_s(const uint2* __restrict__ rec,
        const int* __restrict__ bbase, const float* __restrict__ ws,
        void* __restrict__ out, const void* s6r) {
    const bool bf = detect_bf16(s6r);
    __shared__ float bins[BSZ];
    __shared__ unsigned irow[BSZ * 13];     // 13-dword stride: bank spread
    int b = blockIdx.x;
    int a0 = b << BSH;
    int na = NATOMS - a0; if (na > BSZ) na = BSZ;
    for (int t = threadIdx.x; t < BSZ; t += 512) bins[t] = 0.f;
    const unsigned* betaU = (const unsigned*)(ws + OFF_BETA);
    for (int t = threadIdx.x; t < na * 12; t += 512) {
        int l = t / 12, k = t - l * 12;
        irow[l * 13 + k] = betaU[(size_t)(a0 + l) * 12 + k];
    }
    __syncthreads();
    float s6 = ws[1], s8 = ws[2], a1 = ws[3], a2 = ws[4];
    int bs = bbase[b], be = bbase[b + 1];
    const char* B = (const char*)betaU;
    for (int p = bs + (int)threadIdx.x; p < be; p += 2*512) {
        int p2 = p + 512;
        bool h2 = (p2 < be);
        uint2 r1 = rec[p];
        uint2 r2 = h2 ? rec[p2] : r1;
        int il1 = (r1.x >> 17) & (BSZ-1), j1 = r1.x & 0x1FFFF;
        int il2 = (r2.x >> 17) & (BSZ-1), j2 = r2.x & 0x1FFFF;
        const uint4* J1 = (const uint4*)(B + (size_t)j1 * 48);
        const uint4* J2 = (const uint4*)(B + (size_t)j2 * 48);
        uint4 ja0 = J1[0], ja1 = J1[1], ja2 = J1[2];
        uint4 jb0 = J2[0], jb1 = J2[1], jb2 = J2[2];
        float vi[24], vj[24];
        #pragma unroll
        for (int k = 0; k < 12; ++k) up2(irow[il1*13 + k], vi + 2*k);
        unpack24(ja0, ja1, ja2, vj);
        float e1 = pair_energy(vi, vj, __uint_as_float(r1.y), s6, s8, a1, a2);
        atomicAdd(&bins[il1], e1);
        if (h2) {
            #pragma unroll
            for (int k = 0; k < 12; ++k) up2(irow[il2*13 + k], vi + 2*k);
            unpack24(jb0, jb1, jb2, vj);
            float e2 = pair_energy(vi, vj, __uint_as_float(r2.y), s6, s8, a1, a2);
            atomicAdd(&bins[il2], e2);
        }
    }
    __syncthreads();
    for (int t = threadIdx.x; t < na; t += 512) {
        float v = HALF_HART * bins[t];
        if (bf) ((__hip_bfloat16*)out)[a0 + t] = __float2bfloat16(v);
        else    ((float*)out)[a0 + t] = v;
    }
}

// =================== FALLBACK PATH (round-4, global atomics) =================

__global__ void k_prep_fb(const int* __restrict__ refsys, const int* __restrict__ species,
                          const void* zeff, const void* refh, const void* sscale,
                          const void* secaiw, const void* gam, const void* ascale,
                          const void* alphaiw, const void* hcount, const void* cpw,
                          const void* rcov, const void* en,
                          const void* s6r, const void* s8r, const void* a1r,
                          const void* a2r, const void* sqr,
                          float* __restrict__ ws) {
    const bool bf = detect_bf16(s6r);
    prep_body(blockIdx.x * blockDim.x + threadIdx.x, bf, refsys, species, zeff,
              refh, sscale, secaiw, gam, ascale, alphaiw, hcount, cpw, rcov, en,
              s6r, s8r, a1r, a2r, sqr, ws);
}

__device__ __forceinline__ float2 ldf2(const void* p, int t, bool bf) {
    if (bf) {
        unsigned int u = ((const unsigned int*)p)[t];
        return make_float2(__uint_as_float(u << 16),
                           __uint_as_float(u & 0xFFFF0000u));
    }
    return ((const float2*)p)[t];
}

__global__ void k_ncoord_fb(const int* __restrict__ eidx, const void* lengths,
                            const void* s6r, float* __restrict__ ws) {
    const bool bf = detect_bf16(s6r);
    int t = blockIdx.x * blockDim.x + threadIdx.x;
    if (2*t >= NPAIRS) return;
    int2 ii = ((const int2*)eidx)[t];
    int2 jj = ((const int2*)(eidx + NPAIRS))[t];
    float2 L = ldf2(lengths, t, bf);
    const float2* AD = (const float2*)(ws + OFF_AD);
    float2 ai = AD[ii.x], aj = AD[jj.x];
    float2 bi = AD[ii.y], bj = AD[jj.y];
    float r0  = L.x * INV_BOHR;
    float rc0 = (4.f/3.f) * (ai.x + aj.x);
    float d0  = fabsf(ai.y - aj.y) + CK5;
    float cf0 = CK4 * expf(-(d0*d0) * INV_K6) * 0.5f * (1.f + erff(-CKK * (r0 - rc0) / rc0));
    float r1  = L.y * INV_BOHR;
    float rc1 = (4.f/3.f) * (bi.x + bj.x);
    float d1  = fabsf(bi.y - bj.y) + CK5;
    float cf1 = CK4 * expf(-(d1*d1) * INV_K6) * 0.5f * (1.f + erff(-CKK * (r1 - rc1) / rc1));
    atomicAdd(ws + OFF_NCOORD + ii.x, cf0);
    atomicAdd(ws + OFF_NCOORD + ii.y, cf1);
}

// fallback beta: global tables (alpha is already pre-scaled by prep)
__global__ void k_beta_fb(const int* __restrict__ species, const void* pq,
                          const void* zeff, const void* gam,
                          const void* mask, const void* wght, const void* cn,
                          const void* refq, const void* sq4, const void* s6r,
                          float* __restrict__ ws) {
    const bool bf = detect_bf16(s6r);
    int k = blockIdx.x * blockDim.x + threadIdx.x;
    if (k >= NATOMS) return;
    int sp = species[k];
    float nce = ws[OFF_NCOORD + k];
    float spq = ws[0];
    float gw[NREF];
    float sum = 0.f;
    #pragma unroll
    for (int a = 0; a < NREF; ++a) {
        float g = 0.f;
        #pragma unroll
        for (int c = 0; c < NC; ++c) {
            int idx = (sp*NREF + a)*NC + c;
            float dlt = nce - ldf(cn, idx, bf);
            g += ldf(mask, idx, bf) * expf(-6.f * ldf(wght, idx, bf) * dlt * dlt);
        }
        gw[a] = g; sum += g;
    }
    float inv  = 1.f / fmaxf(sum, 1e-7f);
    float ze   = ldf(zeff, sp, bf);
    float qmod = ze + ldf(pq, k, bf);
    float gm   = ldf(gam, sp, bf);
    float beta[NW];
    #pragma unroll
    for (int w = 0; w < NW; ++w) beta[w] = 0.f;
    const float* A = ws + OFF_ALPHA + sp * (NREF*NW);
    #pragma unroll
    for (int a = 0; a < NREF; ++a) {
        float qref = ze + ldf(refq, sp*NREF + a, bf) * spq;
        float zf = (qmod > 1e-8f)
                 ? expf(3.f * (1.f - expf(2.f * gm * (1.f - qref / qmod))))
                 : E3F;
        float za = zf * gw[a] * inv;
        #pragma unroll
        for (int w = 0; w < NW; ++w) beta[w] = fmaf(A[a*NW + w], za, beta[w]);
    }
    alignas(16) __half hrow[24];
    #pragma unroll
    for (int w = 0; w < NW; ++w) hrow[w] = __float2half(beta[w]);  // alpha pre-scaled
    hrow[23] = __float2half(ldf(sq4, sp, bf));
    uint4* dst = (uint4*)((char*)(ws + OFF_BETA) + (size_t)k * 48);
    const uint4* src = (const uint4*)hrow;
    dst[0] = src[0]; dst[1] = src[1]; dst[2] = src[2];
}

__global__ void k_energy_fb(const int* __restrict__ eidx, const void* lengths,
                            const void* s6r, float* __restrict__ ws) {
    const bool bf = detect_bf16(s6r);
    int t = blockIdx.x * blockDim.x + threadIdx.x;
    if (2*t >= NPAIRS) return;
    int2 ii = ((const int2*)eidx)[t];
    int2 jj = ((const int2*)(eidx + NPAIRS))[t];
    float2 L = ldf2(lengths, t, bf);
    const char* B = (const char*)(ws + OFF_BETA);
    const uint4* qi0 = (const uint4*)(B + (size_t)ii.x * 48);
    const uint4* qj0 = (const uint4*)(B + (size_t)jj.x * 48);
    const uint4* qi1 = (const uint4*)(B + (size_t)ii.y * 48);
    const uint4* qj1 = (const uint4*)(B + (size_t)jj.y * 48);
    uint4 ra0 = qi0[0], ra1 = qi0[1], ra2 = qi0[2];
    uint4 rb0 = qj0[0], rb1 = qj0[1], rb2 = qj0[2];
    uint4 rc0 = qi1[0], rc1 = qi1[1], rc2 = qi1[2];
    uint4 rd0 = qj1[0], rd1 = qj1[1], rd2 = qj1[2];
    float s6 = ws[1], s8 = ws[2], a1 = ws[3], a2 = ws[4];
    float vi[24], vj[24];
    unpack24(ra0, ra1, ra2, vi);
    unpack24(rb0, rb1, rb2, vj);
    float e0 = pair_energy(vi, vj, L.x, s6, s8, a1, a2);
    unpack24(rc0, rc1, rc2, vi);
    unpack24(rd0, rd1, rd2, vj);
    float e1 = pair_energy(vi, vj, L.y, s6, s8, a1, a2);
    atomicAdd(ws + OFF_ENERGY + ii.x, e0);
    atomicAdd(ws + OFF_ENERGY + ii.y, e1);
}

__global__ void k_final(const float* __restrict__ ws, void* out, const void* s6r) {
    const bool bf = detect_bf16(s6r);
    int k = blockIdx.x * blockDim.x + threadIdx.x;
    if (k >= NATOMS) return;
    float v = HALF_HART * ws[OFF_ENERGY + k];
    if (bf) ((__hip_bfloat16*)out)[k] = __float2bfloat16(v);
    else    ((float*)out)[k] = v;
}

// ---- launch ------------------------------------------------------------------
extern "C" void kernel_launch(void* const* d_in, const int* in_sizes, int n_in,
                              void* d_out, int out_size, void* d_ws, size_t ws_size,
                              hipStream_t stream) {
    (void)in_sizes; (void)n_in; (void)out_size;

    const int*  species = (const int*)d_in[0];
    const int*  eidx    = (const int*)d_in[1];
    const void* lengths = d_in[2];
    const void* pq      = d_in[3];
    const void* s6r     = d_in[4];
    const void* s8r     = d_in[5];
    const void* a1r     = d_in[6];
    const void* a2r     = d_in[7];
    const void* sqr     = d_in[8];
    const int*  refsys  = (const int*)d_in[9];
    const void* zeff    = d_in[10];
    const void* refh    = d_in[11];
    const void* sscale  = d_in[12];
    const void* secaiw  = d_in[13];
    const void* gam     = d_in[14];
    const void* ascale  = d_in[15];
    const void* alphaiw = d_in[16];
    const void* hcount  = d_in[17];
    const void* cpw     = d_in[18];
    const void* rcov    = d_in[19];
    const void* en      = d_in[20];
    const void* mask    = d_in[21];
    const void* wght    = d_in[22];
    const void* cn      = d_in[23];
    const void* refq    = d_in[25];
    const void* sq4     = d_in[26];

    float* ws = (float*)d_ws;
    const bool use_sort = (ws_size >= SORT_WS_NEED);

    if (use_sort) {
        int*   hist  = (int*)(ws + OFF_HIST);
        int*   btot  = (int*)(ws + OFF_BTOT);
        int*   bbase = (int*)(ws + OFF_BBASE);
        uint2* rec   = (uint2*)(ws + OFF_REC);

        k_hist        <<<NBLK, 512, 0, stream>>>(eidx, hist, ws);
        k_scan_prep   <<<NB + PREPB, 1024, 0, stream>>>(hist, btot, bbase,
                          refsys, species, zeff, refh, sscale, secaiw, gam,
                          ascale, alphaiw, hcount, cpw, rcov, en,
                          s6r, s8r, a1r, a2r, sqr, ws);
        k_scatter_pack<<<NBLK + PACK_BLKS, 512, 0, stream>>>(eidx, lengths, s6r,
                          hist, bbase, rec, zeff, gam, mask, wght, cn, refq,
                          sq4, ws);
        k_ncbeta      <<<NB, 512, 0, stream>>>(rec, bbase, species, pq, s6r, ws);
        k_energy_s    <<<NB, 512, 0, stream>>>(rec, bbase, ws, d_out, s6r);
    } else {
        hipMemsetAsync(ws + OFF_NCOORD, 0, (size_t)(2 * NATOMS) * sizeof(float), stream);
        k_prep_fb  <<<(NATOMS   + 511)/512, 512, 0, stream>>>(refsys, species,
                        zeff, refh, sscale, secaiw, gam, ascale, alphaiw,
                        hcount, cpw, rcov, en, s6r, s8r, a1r, a2r, sqr, ws);
        k_ncoord_fb<<<(NPAIRS/2 + 255)/256, 256, 0, stream>>>(eidx, lengths, s6r, ws);
        k_beta_fb  <<<(NATOMS   + 255)/256, 256, 0, stream>>>(species, pq, zeff, gam,
                        mask, wght, cn, refq, sq4, s6r, ws);
        k_energy_fb<<<(NPAIRS/2 + 255)/256, 256, 0, stream>>>(eidx, lengths, s6r, ws);
        k_final    <<<(NATOMS   + 255)/256, 256, 0, stream>>>(ws, d_out, s6r);
    }
}

// Round 10
// 100.866 us; speedup vs baseline: 1.0034x; 1.0034x over previous
//
#include <hip/hip_runtime.h>
#include <hip/hip_bf16.h>
#include <hip/hip_fp16.h>

// ---- problem constants -----------------------------------------------------
#define ZZ      87
#define NREF    7
#define NC      5
#define NW      23
#define NATOMS  75000
#define NPAIRS  1500000
#define IAW     (ZZ*NREF*NW)        // 14007 alpha elements

// ---- sort params ------------------------------------------------------------
#define BSH     7                   // bucket = i >> 7
#define BSZ     128                 // atoms per bucket
#define NB      586                 // ceil(NATOMS/BSZ)
#define BLKP    4096                // pairs per hist/scatter block
#define NBLK    367                 // ceil(NPAIRS/BLKP)
#define PREPB   74                  // ceil(75264/1024) prep blocks inside scan kernel
#define PACK_BLKS 22                // ceil(11050/512)

// ---- workspace layout (float offsets) ---------------------------------------
// [0..4] scalars: spq, s6, s8, a1, a2 ; ws[8] (int) = scan done-counter
#define OFF_DONE    8
#define OFF_ALPHA   32              // 14007 (alpha * sqrt(cpw*3/2pi), fp32)
#define OFF_AD      14040           // float2[NATOMS]: (rcov[sp], en[sp])
#define OFF_NCOORD  164040          // 75000 (fallback path only)
#define OFF_ENERGY  239040          // 75000 (fallback accumulator)
#define OFF_IMG     OFF_ENERGY      // sorted path: 14356-dword LDS image lives here
#define OFF_BETA    314048          // half[NATOMS*24] (48B rows, 16B aligned)
#define OFF_HIST    1214048         // int[NBLK*NB] (transposed [blk][b])
#define OFF_BTOT    1643586         // int[NB] (+pad)
#define OFF_BBASE   1644176         // int[NB+1] (+pad)
#define OFF_REC     1644768         // uint2[NPAIRS] (8B aligned: even offset)
#define SORT_WS_NEED      ((size_t)(OFF_REC + 2*NPAIRS) * 4)   // ~17.7 MiB

// ---- LDS image layout (dword offsets inside image) ---------------------------
#define IMG_A   0       // uint[7308]: half2-packed alpha' [87][7][12] (w pairs)
#define IMG_C   7308    // float2[3045]: {cn, wght (masked: <0 if mask==0)}
#define IMG_Q   13398   // float[609]: qref = zeff + refq*spq
#define IMG_G   14008   // float4[87]: {zeff, gam, sqrt_r4r2, 0} (dword 14007 pad)
#define IMG_DW  14356   // = 4*3589, 57.4 KB

static constexpr float INV_BOHR  = (float)(1.0/0.5291772105638411);
static constexpr float HALF_HART = (float)(0.5*27.211386024367243);
static constexpr float CK4 = 4.10451f;
static constexpr float CK5 = 19.08857f;
static constexpr float INV_K6 = (float)(1.0/254.5553148552);
static constexpr float CKK = 7.5f;
static constexpr float E3F = 20.085536923187668f;       // e^3
static constexpr float C32PI = 0.47746482927568606f;    // 3/(2*pi)

// ---- dtype hedge: detect bf16 vs fp32 float tensors from s6_raw bits --------
__device__ __forceinline__ bool detect_bf16(const void* s6raw) {
    return ((*(const unsigned short*)s6raw) >> 8) == 0x3Fu;
}
__device__ __forceinline__ float ldf(const void* p, int i, bool bf) {
    if (bf) {
        unsigned int u = ((const unsigned short*)p)[i];
        return __uint_as_float(u << 16);
    }
    return ((const float*)p)[i];
}
__device__ __forceinline__ float splus(float x) {
    return (x > 15.f) ? x : log1pf(expf(x));
}
__device__ __forceinline__ void up2(unsigned int u, float* d) {
    __half2 h;
    *reinterpret_cast<unsigned int*>(&h) = u;
    float2 f = __half22float2(h);
    d[0] = f.x; d[1] = f.y;
}
__device__ __forceinline__ void unpack24(uint4 a, uint4 b, uint4 c, float* v) {
    up2(a.x, v+0);  up2(a.y, v+2);  up2(a.z, v+4);  up2(a.w, v+6);
    up2(b.x, v+8);  up2(b.y, v+10); up2(b.z, v+12); up2(b.w, v+14);
    up2(c.x, v+16); up2(c.y, v+18); up2(c.z, v+20); up2(c.w, v+22);
}
// 8 consecutive float loads starting at p0 (p0 % 8 == 0)
__device__ __forceinline__ void ld8(const void* p, int p0, bool bf, float* L) {
    if (bf) {
        uint4 u = *(const uint4*)((const unsigned short*)p + p0);
        unsigned vs[4] = {u.x, u.y, u.z, u.w};
        #pragma unroll
        for (int k = 0; k < 4; ++k) {
            L[2*k]   = __uint_as_float(vs[k] << 16);
            L[2*k+1] = __uint_as_float(vs[k] & 0xFFFF0000u);
        }
    } else {
        float4 f0 = *(const float4*)((const float*)p + p0);
        float4 f1 = *(const float4*)((const float*)p + p0 + 4);
        L[0]=f0.x; L[1]=f0.y; L[2]=f0.z; L[3]=f0.w;
        L[4]=f1.x; L[5]=f1.y; L[6]=f1.z; L[7]=f1.w;
    }
}

// ---- shared prep body (t over [0, 75776)) ------------------------------------
__device__ __forceinline__ void prep_body(int t, bool bf,
        const int* __restrict__ refsys, const int* __restrict__ species,
        const void* zeff, const void* refh, const void* sscale,
        const void* secaiw, const void* gam, const void* ascale,
        const void* alphaiw, const void* hcount, const void* cpw,
        const void* rcov, const void* en,
        const void* s6r, const void* s8r, const void* a1r,
        const void* a2r, const void* sqr, float* __restrict__ ws) {
    if (t == 0) {
        ws[0] = splus(ldf(sqr, 0, bf));
        ws[1] = splus(ldf(s6r, 0, bf));
        ws[2] = splus(ldf(s8r, 0, bf));
        ws[3] = splus(ldf(a1r, 0, bf));
        ws[4] = splus(ldf(a2r, 0, bf));
    }
    if (t < NATOMS) {
        int sp = species[t];
        ((float2*)(ws + OFF_AD))[t] = make_float2(ldf(rcov, sp, bf), ldf(en, sp, bf));
    }
    if (t >= IAW) return;
    int w  = t % NW;
    int ia = t / NW;
    int rs = refsys[ia];
    float spq  = splus(ldf(sqr, 0, bf));
    float ze   = ldf(zeff, rs, bf);
    float qmod = ze + ldf(refh, ia, bf) * spq;
    float zfac;
    if (qmod > 1e-8f) {
        float g = ldf(gam, rs, bf);
        zfac = expf(3.f * (1.f - expf(2.f * g * (1.f - ze / qmod))));
    } else {
        zfac = E3F;
    }
    float sec = ldf(sscale, rs, bf) * ldf(secaiw, rs*NW + w, bf) * zfac;
    float al  = ldf(ascale, ia, bf) *
                (ldf(alphaiw, ia*NW + w, bf) - ldf(hcount, ia, bf) * sec);
    float bsw = sqrtf(C32PI * ldf(cpw, w, bf));
    ws[OFF_ALPHA + t] = fmaxf(al, 0.f) * bsw;     // fold sqrt(c_w*3/2pi) here
}

// =================== SORTED PATH (no global atomics in hot loops) =============

// ---- K1: per-block bucket histograms (hist transposed: [blk][b]) -------------
__global__ __launch_bounds__(512) void k_hist(const int* __restrict__ eidx,
                                              int* __restrict__ hist,
                                              float* __restrict__ ws) {
    __shared__ int h[NB];
    int blk = blockIdx.x;
    if (blk == 0 && threadIdx.x == 0) ((int*)ws)[OFF_DONE] = 0;  // reset scan ticket
    for (int t = threadIdx.x; t < NB; t += 512) h[t] = 0;
    __syncthreads();
    int p0 = blk * BLKP + (int)threadIdx.x * 8;
    if (p0 + 8 <= NPAIRS) {                           // NPAIRS % 8 == 0
        int4 a0 = *(const int4*)(eidx + p0);
        int4 a1 = *(const int4*)(eidx + p0 + 4);
        atomicAdd(&h[a0.x >> BSH], 1);
        atomicAdd(&h[a0.y >> BSH], 1);
        atomicAdd(&h[a0.z >> BSH], 1);
        atomicAdd(&h[a0.w >> BSH], 1);
        atomicAdd(&h[a1.x >> BSH], 1);
        atomicAdd(&h[a1.y >> BSH], 1);
        atomicAdd(&h[a1.z >> BSH], 1);
        atomicAdd(&h[a1.w >> BSH], 1);
    }
    __syncthreads();
    for (int t = threadIdx.x; t < NB; t += 512)
        hist[(size_t)blk * NB + t] = h[t];            // coalesced row write
}

// ---- K2: per-bucket scan (blocks [0,586)) + base scan (last block) +
//          prep (blocks [586, 586+74)) -----------------------------------------
__global__ __launch_bounds__(1024) void k_scan_prep(
        int* __restrict__ hist, int* __restrict__ btot, int* __restrict__ bbase,
        const int* __restrict__ refsys, const int* __restrict__ species,
        const void* zeff, const void* refh, const void* sscale,
        const void* secaiw, const void* gam, const void* ascale,
        const void* alphaiw, const void* hcount, const void* cpw,
        const void* rcov, const void* en,
        const void* s6r, const void* s8r, const void* a1r,
        const void* a2r, const void* sqr,
        float* __restrict__ ws) {
    const bool bf = detect_bf16(s6r);
    int blk = blockIdx.x;
    if (blk >= NB) {                                  // ---- prep part ----
        prep_body((blk - NB) * 1024 + (int)threadIdx.x, bf, refsys, species,
                  zeff, refh, sscale, secaiw, gam, ascale, alphaiw, hcount,
                  cpw, rcov, en, s6r, s8r, a1r, a2r, sqr, ws);
        return;
    }
    // ---- per-bucket exclusive scan over NBLK block entries ----
    int b = blk;
    int t = threadIdx.x;
    __shared__ int wsum[16];
    __shared__ int sTicket;
    int v = (t < NBLK) ? hist[(size_t)t * NB + b] : 0;
    int lane = t & 63, wid = t >> 6;
    int x = v;
    #pragma unroll
    for (int d = 1; d < 64; d <<= 1) {
        int n = __shfl_up(x, d, 64);
        if (lane >= d) x += n;
    }
    if (lane == 63) wsum[wid] = x;
    __syncthreads();
    if (t == 0) {
        int acc = 0;
        #pragma unroll
        for (int w = 0; w < 16; ++w) { int s = wsum[w]; wsum[w] = acc; acc += s; }
    }
    __syncthreads();
    int incl = x + wsum[wid];
    if (t < NBLK) hist[(size_t)t * NB + b] = incl - v;   // exclusive
    if (t == 1023) {
        btot[b] = incl;                                   // bucket total
        __threadfence();                                  // publish before ticket
        sTicket = atomicAdd((int*)ws + OFF_DONE, 1);
    }
    __syncthreads();
    if (sTicket != NB - 1) return;
    // ---- last-finishing block: scan bucket totals -> bases ----
    __threadfence();
    int v2 = (t < NB) ? atomicAdd(&btot[t], 0) : 0;       // coherent read
    int x2 = v2;
    #pragma unroll
    for (int d = 1; d < 64; d <<= 1) {
        int n = __shfl_up(x2, d, 64);
        if (lane >= d) x2 += n;
    }
    if (lane == 63) wsum[wid] = x2;
    __syncthreads();
    if (t == 0) {
        int acc = 0;
        #pragma unroll
        for (int w = 0; w < 16; ++w) { int s = wsum[w]; wsum[w] = acc; acc += s; }
    }
    __syncthreads();
    int incl2 = x2 + wsum[wid];
    if (t < NB) bbase[t] = incl2 - v2;
    if (t == 1023) bbase[NB] = incl2;                     // = NPAIRS
}

// ---- K3: scatter (blocks [0,367)) + pack image (blocks [367,367+22)) ---------
__global__ __launch_bounds__(512) void k_scatter_pack(
        const int* __restrict__ eidx, const void* lengths, const void* s6r,
        const int* __restrict__ hist, const int* __restrict__ bbase,
        uint2* __restrict__ rec,
        const void* zeff, const void* gam, const void* mask,
        const void* wght, const void* cn, const void* refq, const void* sq4,
        float* __restrict__ ws) {
    const bool bf = detect_bf16(s6r);
    __shared__ int cnt[NB];
    int blk = blockIdx.x;
    if (blk >= NBLK) {                                // ---- pack part ----
        unsigned* img = (unsigned*)(ws + OFF_IMG);
        int t = (blk - NBLK) * 512 + (int)threadIdx.x;
        if (t < 7308) {                               // alpha' half2 pack
            int row = t / 12, u = t % 12;
            int w0 = 2*u, w1 = 2*u + 1;
            const float* aF = ws + OFF_ALPHA + row * NW;
            float v0 = aF[w0];
            float v1 = (w1 < NW) ? aF[w1] : 0.f;
            unsigned lo = __half_as_ushort(__float2half(v0));
            unsigned hi = __half_as_ushort(__float2half(v1));
            img[t] = lo | (hi << 16);
        } else if (t < 7308 + 3045) {                 // {cn, masked wght}
            int e = t - 7308;                         // e = sp*35 + a*5 + c
            float cnv = ldf(cn, e, bf);
            float wv  = (ldf(mask, e, bf) > 0.5f) ? ldf(wght, e, bf) : -1.f;
            ((float2*)(img + IMG_C))[e] = make_float2(cnv, wv);
        } else if (t < 10353 + 609) {                 // qref = zeff + refq*spq
            int e = t - 10353;                        // e = sp*7 + a
            int sp = e / NREF;
            ((float*)(img + IMG_Q))[e] = ldf(zeff, sp, bf) + ldf(refq, e, bf) * ws[0];
        } else if (t < 10962 + 87) {                  // {zeff, gam, sq4, 0}
            int sp = t - 10962;
            ((float4*)(img + IMG_G))[sp] = make_float4(ldf(zeff, sp, bf),
                                                       ldf(gam, sp, bf),
                                                       ldf(sq4, sp, bf), 0.f);
        } else if (t == 11049) {
            img[14007] = 0;                           // alignment pad
        }
        return;
    }
    // ---- scatter part ----
    const int* hcol = hist + (size_t)blk * NB;        // coalesced row read
    for (int t = threadIdx.x; t < NB; t += 512)
        cnt[t] = bbase[t] + hcol[t];                  // absolute write cursor
    __syncthreads();
    int p0 = blk * BLKP + (int)threadIdx.x * 8;
    if (p0 + 8 > NPAIRS) return;                      // NPAIRS % 8 == 0
    int4 a0 = *(const int4*)(eidx + p0);
    int4 a1 = *(const int4*)(eidx + p0 + 4);
    int4 b0 = *(const int4*)(eidx + NPAIRS + p0);
    int4 b1 = *(const int4*)(eidx + NPAIRS + p0 + 4);
    float L[8];
    ld8(lengths, p0, bf, L);
    int is[8] = {a0.x,a0.y,a0.z,a0.w,a1.x,a1.y,a1.z,a1.w};
    int js[8] = {b0.x,b0.y,b0.z,b0.w,b1.x,b1.y,b1.z,b1.w};
    #pragma unroll
    for (int k = 0; k < 8; ++k) {
        int b = is[k] >> BSH;
        int pos = atomicAdd(&cnt[b], 1);              // LDS atomic -> final pos
        rec[pos] = make_uint2(((unsigned)(is[k] & (BSZ-1)) << 17) | (unsigned)js[k],
                              __float_as_uint(L[k]));
    }
}

// ---- K4: ncoord + beta fused (one block per bucket; ncoord stays in LDS) -----
__global__ __launch_bounds__(512) void k_ncbeta(const uint2* __restrict__ rec,
        const int* __restrict__ bbase, const int* __restrict__ species,
        const void* pq, const void* s6r, float* __restrict__ ws) {
    const bool bf = detect_bf16(s6r);
    __shared__ __align__(16) unsigned s_img[IMG_DW];
    __shared__ float bins[BSZ];
    __shared__ float adl[BSZ * 2];
    int b = blockIdx.x;
    int a0 = b << BSH;
    int na = NATOMS - a0; if (na > BSZ) na = BSZ;
    {   // cooperative image fill (3589 uint4, coalesced, L2-resident)
        const uint4* g4 = (const uint4*)(ws + OFF_IMG);
        uint4* s4 = (uint4*)s_img;
        for (int t = threadIdx.x; t < IMG_DW/4; t += 512) s4[t] = g4[t];
    }
    for (int t = threadIdx.x; t < BSZ; t += 512) bins[t] = 0.f;
    const float2* AD = (const float2*)(ws + OFF_AD);
    for (int t = threadIdx.x; t < na; t += 512) {
        float2 v = AD[a0 + t];
        adl[2*t] = v.x; adl[2*t + 1] = v.y;
    }
    __syncthreads();
    // ---- ncoord pair sweep ----
    int bs = bbase[b], be = bbase[b + 1];
    for (int p = bs + (int)threadIdx.x; p < be; p += 2*512) {
        int p2 = p + 512;
        bool h2 = (p2 < be);
        uint2 r1 = rec[p];
        uint2 r2 = h2 ? rec[p2] : r1;
        int il1 = (r1.x >> 17) & (BSZ-1), j1 = r1.x & 0x1FFFF;
        int il2 = (r2.x >> 17) & (BSZ-1), j2 = r2.x & 0x1FFFF;
        float2 aj1 = AD[j1];
        float2 aj2 = AD[j2];
        {
            float r  = __uint_as_float(r1.y) * INV_BOHR;
            float rc = (4.f/3.f) * (adl[2*il1] + aj1.x);
            float d  = fabsf(adl[2*il1+1] - aj1.y) + CK5;
            float cf = CK4 * expf(-(d*d)*INV_K6) * 0.5f * (1.f + erff(-CKK*(r-rc)/rc));
            atomicAdd(&bins[il1], cf);
        }
        if (h2) {
            float r  = __uint_as_float(r2.y) * INV_BOHR;
            float rc = (4.f/3.f) * (adl[2*il2] + aj2.x);
            float d  = fabsf(adl[2*il2+1] - aj2.y) + CK5;
            float cf = CK4 * expf(-(d*d)*INV_K6) * 0.5f * (1.f + erff(-CKK*(r-rc)/rc));
            atomicAdd(&bins[il2], cf);
        }
    }
    __syncthreads();
    // ---- beta for this bucket's atoms (t < na) ----
    int t = threadIdx.x;
    if (t >= na) return;
    int k = a0 + t;
    const unsigned* sA = s_img;                          // alpha' half2
    const float2*   sC = (const float2*)(s_img + IMG_C); // {cn, masked wght}
    const float*    sQ = (const float*)(s_img + IMG_Q);  // qref
    const float4*   sG = (const float4*)(s_img + IMG_G); // {zeff, gam, sq4}

    int sp = species[k];
    float nce = bins[t];
    float4 zg = sG[sp];
    float qmod = zg.x + ldf(pq, k, bf);

    float gw[NREF];
    float sum = 0.f;
    #pragma unroll
    for (int a = 0; a < NREF; ++a) {
        float g = 0.f;
        #pragma unroll
        for (int c = 0; c < NC; ++c) {
            float2 cw = sC[sp*35 + a*NC + c];
            float dlt = nce - cw.x;
            float e = __expf(-6.f * cw.y * dlt * dlt);
            g += (cw.y > 0.f) ? e : 0.f;                 // mask folded into sign
        }
        gw[a] = g; sum += g;
    }
    float inv = 1.f / fmaxf(sum, 1e-7f);                 // fixgweights dead code

    float2 acc[12];
    #pragma unroll
    for (int u = 0; u < 12; ++u) acc[u] = make_float2(0.f, 0.f);
    #pragma unroll
    for (int a = 0; a < NREF; ++a) {
        float qref = sQ[sp*NREF + a];
        float zf = (qmod > 1e-8f)
                 ? __expf(3.f * (1.f - __expf(2.f * zg.y * (1.f - qref / qmod))))
                 : E3F;
        float za = zf * gw[a] * inv;
        const uint2* ar = (const uint2*)(sA + (sp*NREF + a) * 12);
        #pragma unroll
        for (int u2 = 0; u2 < 6; ++u2) {
            uint2 h = ar[u2];
            float f[4];
            up2(h.x, f); up2(h.y, f+2);
            acc[2*u2].x   = fmaf(f[0], za, acc[2*u2].x);
            acc[2*u2].y   = fmaf(f[1], za, acc[2*u2].y);
            acc[2*u2+1].x = fmaf(f[2], za, acc[2*u2+1].x);
            acc[2*u2+1].y = fmaf(f[3], za, acc[2*u2+1].y);
        }
    }
    alignas(16) __half hrow[24];
    #pragma unroll
    for (int u = 0; u < 12; ++u) {
        hrow[2*u]   = __float2half(acc[u].x);
        hrow[2*u+1] = __float2half(acc[u].y);
    }
    hrow[23] = __float2half(zg.z);                       // sqrt_r4r2[sp]
    uint4* dst = (uint4*)((char*)(ws + OFF_BETA) + (size_t)k * 48);
    const uint4* src = (const uint4*)hrow;
    dst[0] = src[0]; dst[1] = src[1]; dst[2] = src[2];
}

// ---- pair energy -------------------------------------------------------------
__device__ __forceinline__ float pair_energy(const float* vi, const float* vj,
                                             float len, float s6, float s8,
                                             float a1, float a2) {
    float c6 = 0.f;
    #pragma unroll
    for (int w = 0; w < NW; ++w) c6 = fmaf(vi[w], vj[w], c6);
    float rr = 3.f * vi[23] * vj[23];
    float r  = len * INV_BOHR;
    float r2 = r * r;
    float r6 = r2 * r2 * r2;
    float r8 = r6 * r2;
    float r0   = a1 * sqrtf(rr) + a2;
    float r0sq = r0 * r0;
    float r0_6 = r0sq * r0sq * r0sq;
    float r0_8 = r0_6 * r0sq;
    return -c6 * (s6 / (r6 + r0_6) + s8 * rr / (r8 + r0_8));
}

// ---- K5: energy via LDS bins, fused finalize (one block per bucket) ----------
__global__ __launch_bounds__(512) void k_energy_s(const uint2* __restrict__ rec,
        const int* __restrict__ bbase, const float* __restrict__ ws,
        void* __restrict__ out, const void* s6r) {
    const bool bf = detect_bf16(s6r);
    __shared__ float bins[BSZ];
    __shared__ unsigned irow[BSZ * 13];     // 13-dword stride: bank spread
    int b = blockIdx.x;
    int a0 = b << BSH;
    int na = NATOMS - a0; if (na > BSZ) na = BSZ;
    for (int t = threadIdx.x; t < BSZ; t += 512) bins[t] = 0.f;
    const unsigned* betaU = (const unsigned*)(ws + OFF_BETA);
    for (int t = threadIdx.x; t < na * 12; t += 512) {
        int l = t / 12, k = t - l * 12;
        irow[l * 13 + k] = betaU[(size_t)(a0 + l) * 12 + k];
    }
    __syncthreads();
    float s6 = ws[1], s8 = ws[2], a1 = ws[3], a2 = ws[4];
    int bs = bbase[b], be = bbase[b + 1];
    const char* B = (const char*)betaU;
    for (int p = bs + (int)threadIdx.x; p < be; p += 2*512) {
        int p2 = p + 512;
        bool h2 = (p2 < be);
        uint2 r1 = rec[p];
        uint2 r2 = h2 ? rec[p2] : r1;
        int il1 = (r1.x >> 17) & (BSZ-1), j1 = r1.x & 0x1FFFF;
        int il2 = (r2.x >> 17) & (BSZ-1), j2 = r2.x & 0x1FFFF;
        const uint4* J1 = (const uint4*)(B + (size_t)j1 * 48);
        const uint4* J2 = (const uint4*)(B + (size_t)j2 * 48);
        uint4 ja0 = J1[0], ja1 = J1[1], ja2 = J1[2];
        uint4 jb0 = J2[0], jb1 = J2[1], jb2 = J2[2];
        float vi[24], vj[24];
        #pragma unroll
        for (int k = 0; k < 12; ++k) up2(irow[il1*13 + k], vi + 2*k);
        unpack24(ja0, ja1, ja2, vj);
        float e1 = pair_energy(vi, vj, __uint_as_float(r1.y), s6, s8, a1, a2);
        atomicAdd(&bins[il1], e1);
        if (h2) {
            #pragma unroll
            for (int k = 0; k < 12; ++k) up2(irow[il2*13 + k], vi + 2*k);
            unpack24(jb0, jb1, jb2, vj);
            float e2 = pair_energy(vi, vj, __uint_as_float(r2.y), s6, s8, a1, a2);
            atomicAdd(&bins[il2], e2);
        }
    }
    __syncthreads();
    for (int t = threadIdx.x; t < na; t += 512) {
        float v = HALF_HART * bins[t];
        if (bf) ((__hip_bfloat16*)out)[a0 + t] = __float2bfloat16(v);
        else    ((float*)out)[a0 + t] = v;
    }
}

// =================== FALLBACK PATH (round-4, global atomics) =================

__global__ void k_prep_fb(const int* __restrict__ refsys, const int* __restrict__ species,
                          const void* zeff, const void* refh, const void* sscale,
                          const void* secaiw, const void* gam, const void* ascale,
                          const void* alphaiw, const void* hcount, const void* cpw,
                          const void* rcov, const void* en,
                          const void* s6r, const void* s8r, const void* a1r,
                          const void* a2r, const void* sqr,
                          float* __restrict__ ws) {
    const bool bf = detect_bf16(s6r);
    prep_body(blockIdx.x * blockDim.x + threadIdx.x, bf, refsys, species, zeff,
              refh, sscale, secaiw, gam, ascale, alphaiw, hcount, cpw, rcov, en,
              s6r, s8r, a1r, a2r, sqr, ws);
}

__device__ __forceinline__ float2 ldf2(const void* p, int t, bool bf) {
    if (bf) {
        unsigned int u = ((const unsigned int*)p)[t];
        return make_float2(__uint_as_float(u << 16),
                           __uint_as_float(u & 0xFFFF0000u));
    }
    return ((const float2*)p)[t];
}

__global__ void k_ncoord_fb(const int* __restrict__ eidx, const void* lengths,
                            const void* s6r, float* __restrict__ ws) {
    const bool bf = detect_bf16(s6r);
    int t = blockIdx.x * blockDim.x + threadIdx.x;
    if (2*t >= NPAIRS) return;
    int2 ii = ((const int2*)eidx)[t];
    int2 jj = ((const int2*)(eidx + NPAIRS))[t];
    float2 L = ldf2(lengths, t, bf);
    const float2* AD = (const float2*)(ws + OFF_AD);
    float2 ai = AD[ii.x], aj = AD[jj.x];
    float2 bi = AD[ii.y], bj = AD[jj.y];
    float r0  = L.x * INV_BOHR;
    float rc0 = (4.f/3.f) * (ai.x + aj.x);
    float d0  = fabsf(ai.y - aj.y) + CK5;
    float cf0 = CK4 * expf(-(d0*d0) * INV_K6) * 0.5f * (1.f + erff(-CKK * (r0 - rc0) / rc0));
    float r1  = L.y * INV_BOHR;
    float rc1 = (4.f/3.f) * (bi.x + bj.x);
    float d1  = fabsf(bi.y - bj.y) + CK5;
    float cf1 = CK4 * expf(-(d1*d1) * INV_K6) * 0.5f * (1.f + erff(-CKK * (r1 - rc1) / rc1));
    atomicAdd(ws + OFF_NCOORD + ii.x, cf0);
    atomicAdd(ws + OFF_NCOORD + ii.y, cf1);
}

// fallback beta: global tables (alpha is already pre-scaled by prep)
__global__ void k_beta_fb(const int* __restrict__ species, const void* pq,
                          const void* zeff, const void* gam,
                          const void* mask, const void* wght, const void* cn,
                          const void* refq, const void* sq4, const void* s6r,
                          float* __restrict__ ws) {
    const bool bf = detect_bf16(s6r);
    int k = blockIdx.x * blockDim.x + threadIdx.x;
    if (k >= NATOMS) return;
    int sp = species[k];
    float nce = ws[OFF_NCOORD + k];
    float spq = ws[0];
    float gw[NREF];
    float sum = 0.f;
    #pragma unroll
    for (int a = 0; a < NREF; ++a) {
        float g = 0.f;
        #pragma unroll
        for (int c = 0; c < NC; ++c) {
            int idx = (sp*NREF + a)*NC + c;
            float dlt = nce - ldf(cn, idx, bf);
            g += ldf(mask, idx, bf) * expf(-6.f * ldf(wght, idx, bf) * dlt * dlt);
        }
        gw[a] = g; sum += g;
    }
    float inv  = 1.f / fmaxf(sum, 1e-7f);
    float ze   = ldf(zeff, sp, bf);
    float qmod = ze + ldf(pq, k, bf);
    float gm   = ldf(gam, sp, bf);
    float beta[NW];
    #pragma unroll
    for (int w = 0; w < NW; ++w) beta[w] = 0.f;
    const float* A = ws + OFF_ALPHA + sp * (NREF*NW);
    #pragma unroll
    for (int a = 0; a < NREF; ++a) {
        float qref = ze + ldf(refq, sp*NREF + a, bf) * spq;
        float zf = (qmod > 1e-8f)
                 ? expf(3.f * (1.f - expf(2.f * gm * (1.f - qref / qmod))))
                 : E3F;
        float za = zf * gw[a] * inv;
        #pragma unroll
        for (int w = 0; w < NW; ++w) beta[w] = fmaf(A[a*NW + w], za, beta[w]);
    }
    alignas(16) __half hrow[24];
    #pragma unroll
    for (int w = 0; w < NW; ++w) hrow[w] = __float2half(beta[w]);  // alpha pre-scaled
    hrow[23] = __float2half(ldf(sq4, sp, bf));
    uint4* dst = (uint4*)((char*)(ws + OFF_BETA) + (size_t)k * 48);
    const uint4* src = (const uint4*)hrow;
    dst[0] = src[0]; dst[1] = src[1]; dst[2] = src[2];
}

__global__ void k_energy_fb(const int* __restrict__ eidx, const void* lengths,
                            const void* s6r, float* __restrict__ ws) {
    const bool bf = detect_bf16(s6r);
    int t = blockIdx.x * blockDim.x + threadIdx.x;
    if (2*t >= NPAIRS) return;
    int2 ii = ((const int2*)eidx)[t];
    int2 jj = ((const int2*)(eidx + NPAIRS))[t];
    float2 L = ldf2(lengths, t, bf);
    const char* B = (const char*)(ws + OFF_BETA);
    const uint4* qi0 = (const uint4*)(B + (size_t)ii.x * 48);
    const uint4* qj0 = (const uint4*)(B + (size_t)jj.x * 48);
    const uint4* qi1 = (const uint4*)(B + (size_t)ii.y * 48);
    const uint4* qj1 = (const uint4*)(B + (size_t)jj.y * 48);
    uint4 ra0 = qi0[0], ra1 = qi0[1], ra2 = qi0[2];
    uint4 rb0 = qj0[0], rb1 = qj0[1], rb2 = qj0[2];
    uint4 rc0 = qi1[0], rc1 = qi1[1], rc2 = qi1[2];
    uint4 rd0 = qj1[0], rd1 = qj1[1], rd2 = qj1[2];
    float s6 = ws[1], s8 = ws[2], a1 = ws[3], a2 = ws[4];
    float vi[24], vj[24];
    unpack24(ra0, ra1, ra2, vi);
    unpack24(rb0, rb1, rb2, vj);
    float e0 = pair_energy(vi, vj, L.x, s6, s8, a1, a2);
    unpack24(rc0, rc1, rc2, vi);
    unpack24(rd0, rd1, rd2, vj);
    float e1 = pair_energy(vi, vj, L.y, s6, s8, a1, a2);
    atomicAdd(ws + OFF_ENERGY + ii.x, e0);
    atomicAdd(ws + OFF_ENERGY + ii.y, e1);
}

__global__ void k_final(const float* __restrict__ ws, void* out, const void* s6r) {
    const bool bf = detect_bf16(s6r);
    int k = blockIdx.x * blockDim.x + threadIdx.x;
    if (k >= NATOMS) return;
    float v = HALF_HART * ws[OFF_ENERGY + k];
    if (bf) ((__hip_bfloat16*)out)[k] = __float2bfloat16(v);
    else    ((float*)out)[k] = v;
}

// ---- launch ------------------------------------------------------------------
extern "C" void kernel_launch(void* const* d_in, const int* in_sizes, int n_in,
                              void* d_out, int out_size, void* d_ws, size_t ws_size,
                              hipStream_t stream) {
    (void)in_sizes; (void)n_in; (void)out_size;

    const int*  species = (const int*)d_in[0];
    const int*  eidx    = (const int*)d_in[1];
    const void* lengths = d_in[2];
    const void* pq      = d_in[3];
    const void* s6r     = d_in[4];
    const void* s8r     = d_in[5];
    const void* a1r     = d_in[6];
    const void* a2r     = d_in[7];
    const void* sqr     = d_in[8];
    const int*  refsys  = (const int*)d_in[9];
    const void* zeff    = d_in[10];
    const void* refh    = d_in[11];
    const void* sscale  = d_in[12];
    const void* secaiw  = d_in[13];
    const void* gam     = d_in[14];
    const void* ascale  = d_in[15];
    const void* alphaiw = d_in[16];
    const void* hcount  = d_in[17];
    const void* cpw     = d_in[18];
    const void* rcov    = d_in[19];
    const void* en      = d_in[20];
    const void* mask    = d_in[21];
    const void* wght    = d_in[22];
    const void* cn      = d_in[23];
    const void* refq    = d_in[25];
    const void* sq4     = d_in[26];

    float* ws = (float*)d_ws;
    const bool use_sort = (ws_size >= SORT_WS_NEED);

    if (use_sort) {
        int*   hist  = (int*)(ws + OFF_HIST);
        int*   btot  = (int*)(ws + OFF_BTOT);
        int*   bbase = (int*)(ws + OFF_BBASE);
        uint2* rec   = (uint2*)(ws + OFF_REC);

        k_hist        <<<NBLK, 512, 0, stream>>>(eidx, hist, ws);
        k_scan_prep   <<<NB + PREPB, 1024, 0, stream>>>(hist, btot, bbase,
                          refsys, species, zeff, refh, sscale, secaiw, gam,
                          ascale, alphaiw, hcount, cpw, rcov, en,
                          s6r, s8r, a1r, a2r, sqr, ws);
        k_scatter_pack<<<NBLK + PACK_BLKS, 512, 0, stream>>>(eidx, lengths, s6r,
                          hist, bbase, rec, zeff, gam, mask, wght, cn, refq,
                          sq4, ws);
        k_ncbeta      <<<NB, 512, 0, stream>>>(rec, bbase, species, pq, s6r, ws);
        k_energy_s    <<<NB, 512, 0, stream>>>(rec, bbase, ws, d_out, s6r);
    } else {
        hipMemsetAsync(ws + OFF_NCOORD, 0, (size_t)(2 * NATOMS) * sizeof(float), stream);
        k_prep_fb  <<<(NATOMS   + 511)/512, 512, 0, stream>>>(refsys, species,
                        zeff, refh, sscale, secaiw, gam, ascale, alphaiw,
                        hcount, cpw, rcov, en, s6r, s8r, a1r, a2r, sqr, ws);
        k_ncoord_fb<<<(NPAIRS/2 + 255)/256, 256, 0, stream>>>(eidx, lengths, s6r, ws);
        k_beta_fb  <<<(NATOMS   + 255)/256, 256, 0, stream>>>(species, pq, zeff, gam,
                        mask, wght, cn, refq, sq4, s6r, ws);
        k_energy_fb<<<(NPAIRS/2 + 255)/256, 256, 0, stream>>>(eidx, lengths, s6r, ws);
        k_final    <<<(NATOMS   + 255)/256, 256, 0, stream>>>(ws, d_out, s6r);
    }
}

// Round 11
// 74.902 us; speedup vs baseline: 1.3512x; 1.3466x over previous
//
#include <hip/hip_runtime.h>
#include <hip/hip_bf16.h>
#include <hip/hip_fp16.h>

// ---- problem constants -----------------------------------------------------
#define ZZ      87
#define NREF    7
#define NC      5
#define NW      23
#define NATOMS  75000
#define NPAIRS  1500000
#define IAW     (ZZ*NREF*NW)        // 14007 alpha elements

// ---- sort params ------------------------------------------------------------
#define BSH     7                   // bucket = i >> 7
#define BSZ     128                 // atoms per bucket
#define NB      586                 // ceil(NATOMS/BSZ)
#define BLKP    4096                // pairs per hist/scatter block
#define NBLK    367                 // ceil(NPAIRS/BLKP)
#define PREP_BLKS 147               // ceil(NATOMS/512)
#define PACK_BLKS 22                // ceil(11050/512)

// NOTE (round-10 post-mortem): fusing scan_base into scan_bucket via a
// done-ticket (device-scope atomic + threadfence per block tail) REGRESSED
// 75->101 us. Do not retry grid-level sync fusion here; the 1-block
// k_scan_base dispatch costs ~2 us and is the cheaper option.

// ---- workspace layout (float offsets) ---------------------------------------
// [0..4] scalars: spq, s6, s8, a1, a2
#define OFF_ALPHA   32              // 14007 (alpha * sqrt(cpw*3/2pi), fp32)
#define OFF_AD      14040           // float2[NATOMS]: (rcov[sp], en[sp])
#define OFF_NCOORD  164040          // 75000 (fallback path only)
#define OFF_ENERGY  239040          // 75000 (fallback accumulator)
#define OFF_IMG     OFF_ENERGY      // sorted path: 14356-dword LDS image lives here
#define OFF_BETA    314048          // half[NATOMS*24] (48B rows, 16B aligned)
#define OFF_HIST    1214048         // int[NBLK*NB] (transposed [blk][b])
#define OFF_BTOT    1643586         // int[NB] (+pad)
#define OFF_BBASE   1644176         // int[NB+1] (+pad)
#define OFF_REC     1644768         // uint2[NPAIRS] (8B aligned: even offset)
#define SORT_WS_NEED      ((size_t)(OFF_REC + 2*NPAIRS) * 4)   // ~17.7 MiB

// ---- LDS image layout (dword offsets inside image) ---------------------------
#define IMG_A   0       // uint[7308]: half2-packed alpha' [87][7][12] (w pairs)
#define IMG_C   7308    // float2[3045]: {cn, wght (masked: <0 if mask==0)}
#define IMG_Q   13398   // float[609]: qref = zeff + refq*spq
#define IMG_G   14008   // float4[87]: {zeff, gam, sqrt_r4r2, 0} (dword 14007 pad)
#define IMG_DW  14356   // = 4*3589, 57.4 KB

static constexpr float INV_BOHR  = (float)(1.0/0.5291772105638411);
static constexpr float HALF_HART = (float)(0.5*27.211386024367243);
static constexpr float CK4 = 4.10451f;
static constexpr float CK5 = 19.08857f;
static constexpr float INV_K6 = (float)(1.0/254.5553148552);
static constexpr float CKK = 7.5f;
static constexpr float E3F = 20.085536923187668f;       // e^3
static constexpr float C32PI = 0.47746482927568606f;    // 3/(2*pi)

// ---- dtype hedge: detect bf16 vs fp32 float tensors from s6_raw bits --------
__device__ __forceinline__ bool detect_bf16(const void* s6raw) {
    return ((*(const unsigned short*)s6raw) >> 8) == 0x3Fu;
}
__device__ __forceinline__ float ldf(const void* p, int i, bool bf) {
    if (bf) {
        unsigned int u = ((const unsigned short*)p)[i];
        return __uint_as_float(u << 16);
    }
    return ((const float*)p)[i];
}
__device__ __forceinline__ float splus(float x) {
    return (x > 15.f) ? x : log1pf(expf(x));
}
__device__ __forceinline__ void up2(unsigned int u, float* d) {
    __half2 h;
    *reinterpret_cast<unsigned int*>(&h) = u;
    float2 f = __half22float2(h);
    d[0] = f.x; d[1] = f.y;
}
__device__ __forceinline__ void unpack24(uint4 a, uint4 b, uint4 c, float* v) {
    up2(a.x, v+0);  up2(a.y, v+2);  up2(a.z, v+4);  up2(a.w, v+6);
    up2(b.x, v+8);  up2(b.y, v+10); up2(b.z, v+12); up2(b.w, v+14);
    up2(c.x, v+16); up2(c.y, v+18); up2(c.z, v+20); up2(c.w, v+22);
}
// 8 consecutive float loads starting at p0 (p0 % 8 == 0)
__device__ __forceinline__ void ld8(const void* p, int p0, bool bf, float* L) {
    if (bf) {
        uint4 u = *(const uint4*)((const unsigned short*)p + p0);
        unsigned vs[4] = {u.x, u.y, u.z, u.w};
        #pragma unroll
        for (int k = 0; k < 4; ++k) {
            L[2*k]   = __uint_as_float(vs[k] << 16);
            L[2*k+1] = __uint_as_float(vs[k] & 0xFFFF0000u);
        }
    } else {
        float4 f0 = *(const float4*)((const float*)p + p0);
        float4 f1 = *(const float4*)((const float*)p + p0 + 4);
        L[0]=f0.x; L[1]=f0.y; L[2]=f0.z; L[3]=f0.w;
        L[4]=f1.x; L[5]=f1.y; L[6]=f1.z; L[7]=f1.w;
    }
}

// ---- shared prep body (t over [0, 75264)) ------------------------------------
__device__ __forceinline__ void prep_body(int t, bool bf,
        const int* __restrict__ refsys, const int* __restrict__ species,
        const void* zeff, const void* refh, const void* sscale,
        const void* secaiw, const void* gam, const void* ascale,
        const void* alphaiw, const void* hcount, const void* cpw,
        const void* rcov, const void* en,
        const void* s6r, const void* s8r, const void* a1r,
        const void* a2r, const void* sqr, float* __restrict__ ws) {
    if (t == 0) {
        ws[0] = splus(ldf(sqr, 0, bf));
        ws[1] = splus(ldf(s6r, 0, bf));
        ws[2] = splus(ldf(s8r, 0, bf));
        ws[3] = splus(ldf(a1r, 0, bf));
        ws[4] = splus(ldf(a2r, 0, bf));
    }
    if (t < NATOMS) {
        int sp = species[t];
        ((float2*)(ws + OFF_AD))[t] = make_float2(ldf(rcov, sp, bf), ldf(en, sp, bf));
    }
    if (t >= IAW) return;
    int w  = t % NW;
    int ia = t / NW;
    int rs = refsys[ia];
    float spq  = splus(ldf(sqr, 0, bf));
    float ze   = ldf(zeff, rs, bf);
    float qmod = ze + ldf(refh, ia, bf) * spq;
    float zfac;
    if (qmod > 1e-8f) {
        float g = ldf(gam, rs, bf);
        zfac = expf(3.f * (1.f - expf(2.f * g * (1.f - ze / qmod))));
    } else {
        zfac = E3F;
    }
    float sec = ldf(sscale, rs, bf) * ldf(secaiw, rs*NW + w, bf) * zfac;
    float al  = ldf(ascale, ia, bf) *
                (ldf(alphaiw, ia*NW + w, bf) - ldf(hcount, ia, bf) * sec);
    float bsw = sqrtf(C32PI * ldf(cpw, w, bf));
    ws[OFF_ALPHA + t] = fmaxf(al, 0.f) * bsw;     // fold sqrt(c_w*3/2pi) here
}

// =================== SORTED PATH (no global atomics in hot loops) =============

// ---- A: prep (blocks [0,147)) + per-block histograms (blocks [147,147+367)) --
__global__ __launch_bounds__(512) void k_prep_hist(
        const int* __restrict__ refsys, const int* __restrict__ species,
        const void* zeff, const void* refh, const void* sscale,
        const void* secaiw, const void* gam, const void* ascale,
        const void* alphaiw, const void* hcount, const void* cpw,
        const void* rcov, const void* en,
        const void* s6r, const void* s8r, const void* a1r,
        const void* a2r, const void* sqr,
        const int* __restrict__ eidx, int* __restrict__ hist,
        float* __restrict__ ws) {
    const bool bf = detect_bf16(s6r);
    __shared__ int h[NB];
    int blk = blockIdx.x;
    if (blk < PREP_BLKS) {
        prep_body(blk * 512 + (int)threadIdx.x, bf, refsys, species, zeff, refh,
                  sscale, secaiw, gam, ascale, alphaiw, hcount, cpw, rcov, en,
                  s6r, s8r, a1r, a2r, sqr, ws);
        return;
    }
    int hb = blk - PREP_BLKS;
    for (int t = threadIdx.x; t < NB; t += 512) h[t] = 0;
    __syncthreads();
    int p0 = hb * BLKP + (int)threadIdx.x * 8;
    if (p0 + 8 <= NPAIRS) {                           // NPAIRS % 8 == 0
        int4 a0 = *(const int4*)(eidx + p0);
        int4 a1 = *(const int4*)(eidx + p0 + 4);
        atomicAdd(&h[a0.x >> BSH], 1);
        atomicAdd(&h[a0.y >> BSH], 1);
        atomicAdd(&h[a0.z >> BSH], 1);
        atomicAdd(&h[a0.w >> BSH], 1);
        atomicAdd(&h[a1.x >> BSH], 1);
        atomicAdd(&h[a1.y >> BSH], 1);
        atomicAdd(&h[a1.z >> BSH], 1);
        atomicAdd(&h[a1.w >> BSH], 1);
    }
    __syncthreads();
    for (int t = threadIdx.x; t < NB; t += 512)
        hist[(size_t)hb * NB + t] = h[t];             // coalesced row write
}

// ---- B: per-bucket exclusive scan over blocks --------------------------------
__global__ __launch_bounds__(1024) void k_scan_bucket(int* __restrict__ hist,
                                                      int* __restrict__ btot) {
    int b = blockIdx.x;
    int t = threadIdx.x;
    int v = (t < NBLK) ? hist[(size_t)t * NB + b] : 0;
    int lane = t & 63, wid = t >> 6;
    int x = v;
    #pragma unroll
    for (int d = 1; d < 64; d <<= 1) {
        int n = __shfl_up(x, d, 64);
        if (lane >= d) x += n;
    }
    __shared__ int wsum[16];
    if (lane == 63) wsum[wid] = x;
    __syncthreads();
    if (t == 0) {
        int acc = 0;
        #pragma unroll
        for (int w = 0; w < 16; ++w) { int s = wsum[w]; wsum[w] = acc; acc += s; }
    }
    __syncthreads();
    int incl = x + wsum[wid];
    if (t < NBLK) hist[(size_t)t * NB + b] = incl - v;   // exclusive
    if (t == 1023) btot[b] = incl;                        // bucket total
}

// ---- C: scan bucket totals -> bucket bases ----------------------------------
__global__ __launch_bounds__(1024) void k_scan_base(const int* __restrict__ btot,
                                                    int* __restrict__ bbase) {
    int t = threadIdx.x;
    int v = (t < NB) ? btot[t] : 0;
    int lane = t & 63, wid = t >> 6;
    int x = v;
    #pragma unroll
    for (int d = 1; d < 64; d <<= 1) {
        int n = __shfl_up(x, d, 64);
        if (lane >= d) x += n;
    }
    __shared__ int wsum[16];
    if (lane == 63) wsum[wid] = x;
    __syncthreads();
    if (t == 0) {
        int acc = 0;
        #pragma unroll
        for (int w = 0; w < 16; ++w) { int s = wsum[w]; wsum[w] = acc; acc += s; }
    }
    __syncthreads();
    int incl = x + wsum[wid];
    if (t < NB) bbase[t] = incl - v;
    if (t == 1023) bbase[NB] = incl;                        // = NPAIRS
}

// ---- D: scatter (blocks [0,367)) + pack image (blocks [367,367+22)) ---------
__global__ __launch_bounds__(512) void k_scatter_pack(
        const int* __restrict__ eidx, const void* lengths, const void* s6r,
        const int* __restrict__ hist, const int* __restrict__ bbase,
        uint2* __restrict__ rec,
        const void* zeff, const void* gam, const void* mask,
        const void* wght, const void* cn, const void* refq, const void* sq4,
        float* __restrict__ ws) {
    const bool bf = detect_bf16(s6r);
    __shared__ int cnt[NB];
    int blk = blockIdx.x;
    if (blk >= NBLK) {                                // ---- pack part ----
        unsigned* img = (unsigned*)(ws + OFF_IMG);
        int t = (blk - NBLK) * 512 + (int)threadIdx.x;
        if (t < 7308) {                               // alpha' half2 pack
            int row = t / 12, u = t % 12;
            int w0 = 2*u, w1 = 2*u + 1;
            const float* aF = ws + OFF_ALPHA + row * NW;
            float v0 = aF[w0];
            float v1 = (w1 < NW) ? aF[w1] : 0.f;
            unsigned lo = __half_as_ushort(__float2half(v0));
            unsigned hi = __half_as_ushort(__float2half(v1));
            img[t] = lo | (hi << 16);
        } else if (t < 7308 + 3045) {                 // {cn, masked wght}
            int e = t - 7308;                         // e = sp*35 + a*5 + c
            float cnv = ldf(cn, e, bf);
            float wv  = (ldf(mask, e, bf) > 0.5f) ? ldf(wght, e, bf) : -1.f;
            ((float2*)(img + IMG_C))[e] = make_float2(cnv, wv);
        } else if (t < 10353 + 609) {                 // qref = zeff + refq*spq
            int e = t - 10353;                        // e = sp*7 + a
            int sp = e / NREF;
            ((float*)(img + IMG_Q))[e] = ldf(zeff, sp, bf) + ldf(refq, e, bf) * ws[0];
        } else if (t < 10962 + 87) {                  // {zeff, gam, sq4, 0}
            int sp = t - 10962;
            ((float4*)(img + IMG_G))[sp] = make_float4(ldf(zeff, sp, bf),
                                                       ldf(gam, sp, bf),
                                                       ldf(sq4, sp, bf), 0.f);
        } else if (t == 11049) {
            img[14007] = 0;                           // alignment pad
        }
        return;
    }
    // ---- scatter part ----
    const int* hcol = hist + (size_t)blk * NB;        // coalesced row read
    for (int t = threadIdx.x; t < NB; t += 512)
        cnt[t] = bbase[t] + hcol[t];                  // absolute write cursor
    __syncthreads();
    int p0 = blk * BLKP + (int)threadIdx.x * 8;
    if (p0 + 8 > NPAIRS) return;                      // NPAIRS % 8 == 0
    int4 a0 = *(const int4*)(eidx + p0);
    int4 a1 = *(const int4*)(eidx + p0 + 4);
    int4 b0 = *(const int4*)(eidx + NPAIRS + p0);
    int4 b1 = *(const int4*)(eidx + NPAIRS + p0 + 4);
    float L[8];
    ld8(lengths, p0, bf, L);
    int is[8] = {a0.x,a0.y,a0.z,a0.w,a1.x,a1.y,a1.z,a1.w};
    int js[8] = {b0.x,b0.y,b0.z,b0.w,b1.x,b1.y,b1.z,b1.w};
    #pragma unroll
    for (int k = 0; k < 8; ++k) {
        int b = is[k] >> BSH;
        int pos = atomicAdd(&cnt[b], 1);              // LDS atomic -> final pos
        rec[pos] = make_uint2(((unsigned)(is[k] & (BSZ-1)) << 17) | (unsigned)js[k],
                              __float_as_uint(L[k]));
    }
}

// ---- E: ncoord + beta fused (one block per bucket; ncoord stays in LDS) ------
__global__ __launch_bounds__(512) void k_ncbeta(const uint2* __restrict__ rec,
        const int* __restrict__ bbase, const int* __restrict__ species,
        const void* pq, const void* s6r, float* __restrict__ ws) {
    const bool bf = detect_bf16(s6r);
    __shared__ __align__(16) unsigned s_img[IMG_DW];
    __shared__ float bins[BSZ];
    __shared__ float adl[BSZ * 2];
    int b = blockIdx.x;
    int a0 = b << BSH;
    int na = NATOMS - a0; if (na > BSZ) na = BSZ;
    {   // cooperative image fill (3589 uint4, coalesced, L2-resident)
        const uint4* g4 = (const uint4*)(ws + OFF_IMG);
        uint4* s4 = (uint4*)s_img;
        for (int t = threadIdx.x; t < IMG_DW/4; t += 512) s4[t] = g4[t];
    }
    for (int t = threadIdx.x; t < BSZ; t += 512) bins[t] = 0.f;
    const float2* AD = (const float2*)(ws + OFF_AD);
    for (int t = threadIdx.x; t < na; t += 512) {
        float2 v = AD[a0 + t];
        adl[2*t] = v.x; adl[2*t + 1] = v.y;
    }
    __syncthreads();
    // ---- ncoord pair sweep ----
    int bs = bbase[b], be = bbase[b + 1];
    for (int p = bs + (int)threadIdx.x; p < be; p += 2*512) {
        int p2 = p + 512;
        bool h2 = (p2 < be);
        uint2 r1 = rec[p];
        uint2 r2 = h2 ? rec[p2] : r1;
        int il1 = (r1.x >> 17) & (BSZ-1), j1 = r1.x & 0x1FFFF;
        int il2 = (r2.x >> 17) & (BSZ-1), j2 = r2.x & 0x1FFFF;
        float2 aj1 = AD[j1];
        float2 aj2 = AD[j2];
        {
            float r  = __uint_as_float(r1.y) * INV_BOHR;
            float rc = (4.f/3.f) * (adl[2*il1] + aj1.x);
            float d  = fabsf(adl[2*il1+1] - aj1.y) + CK5;
            float cf = CK4 * expf(-(d*d)*INV_K6) * 0.5f * (1.f + erff(-CKK*(r-rc)/rc));
            atomicAdd(&bins[il1], cf);
        }
        if (h2) {
            float r  = __uint_as_float(r2.y) * INV_BOHR;
            float rc = (4.f/3.f) * (adl[2*il2] + aj2.x);
            float d  = fabsf(adl[2*il2+1] - aj2.y) + CK5;
            float cf = CK4 * expf(-(d*d)*INV_K6) * 0.5f * (1.f + erff(-CKK*(r-rc)/rc));
            atomicAdd(&bins[il2], cf);
        }
    }
    __syncthreads();
    // ---- beta for this bucket's atoms (t < na) ----
    int t = threadIdx.x;
    if (t >= na) return;
    int k = a0 + t;
    const unsigned* sA = s_img;                          // alpha' half2
    const float2*   sC = (const float2*)(s_img + IMG_C); // {cn, masked wght}
    const float*    sQ = (const float*)(s_img + IMG_Q);  // qref
    const float4*   sG = (const float4*)(s_img + IMG_G); // {zeff, gam, sq4}

    int sp = species[k];
    float nce = bins[t];
    float4 zg = sG[sp];
    float qmod = zg.x + ldf(pq, k, bf);

    float gw[NREF];
    float sum = 0.f;
    #pragma unroll
    for (int a = 0; a < NREF; ++a) {
        float g = 0.f;
        #pragma unroll
        for (int c = 0; c < NC; ++c) {
            float2 cw = sC[sp*35 + a*NC + c];
            float dlt = nce - cw.x;
            float e = __expf(-6.f * cw.y * dlt * dlt);
            g += (cw.y > 0.f) ? e : 0.f;                 // mask folded into sign
        }
        gw[a] = g; sum += g;
    }
    float inv = 1.f / fmaxf(sum, 1e-7f);                 // fixgweights dead code

    float2 acc[12];
    #pragma unroll
    for (int u = 0; u < 12; ++u) acc[u] = make_float2(0.f, 0.f);
    #pragma unroll
    for (int a = 0; a < NREF; ++a) {
        float qref = sQ[sp*NREF + a];
        float zf = (qmod > 1e-8f)
                 ? __expf(3.f * (1.f - __expf(2.f * zg.y * (1.f - qref / qmod))))
                 : E3F;
        float za = zf * gw[a] * inv;
        const uint2* ar = (const uint2*)(sA + (sp*NREF + a) * 12);
        #pragma unroll
        for (int u2 = 0; u2 < 6; ++u2) {
            uint2 h = ar[u2];
            float f[4];
            up2(h.x, f); up2(h.y, f+2);
            acc[2*u2].x   = fmaf(f[0], za, acc[2*u2].x);
            acc[2*u2].y   = fmaf(f[1], za, acc[2*u2].y);
            acc[2*u2+1].x = fmaf(f[2], za, acc[2*u2+1].x);
            acc[2*u2+1].y = fmaf(f[3], za, acc[2*u2+1].y);
        }
    }
    alignas(16) __half hrow[24];
    #pragma unroll
    for (int u = 0; u < 12; ++u) {
        hrow[2*u]   = __float2half(acc[u].x);
        hrow[2*u+1] = __float2half(acc[u].y);
    }
    hrow[23] = __float2half(zg.z);                       // sqrt_r4r2[sp]
    uint4* dst = (uint4*)((char*)(ws + OFF_BETA) + (size_t)k * 48);
    const uint4* src = (const uint4*)hrow;
    dst[0] = src[0]; dst[1] = src[1]; dst[2] = src[2];
}

// ---- pair energy -------------------------------------------------------------
__device__ __forceinline__ float pair_energy(const float* vi, const float* vj,
                                             float len, float s6, float s8,
                                             float a1, float a2) {
    float c6 = 0.f;
    #pragma unroll
    for (int w = 0; w < NW; ++w) c6 = fmaf(vi[w], vj[w], c6);
    float rr = 3.f * vi[23] * vj[23];
    float r  = len * INV_BOHR;
    float r2 = r * r;
    float r6 = r2 * r2 * r2;
    float r8 = r6 * r2;
    float r0   = a1 * sqrtf(rr) + a2;
    float r0sq = r0 * r0;
    float r0_6 = r0sq * r0sq * r0sq;
    float r0_8 = r0_6 * r0sq;
    return -c6 * (s6 / (r6 + r0_6) + s8 * rr / (r8 + r0_8));
}

// ---- F: energy via LDS bins, fused finalize (one block per bucket) -----------
__global__ __launch_bounds__(512) void k_energy_s(const uint2* __restrict__ rec,
        const int* __restrict__ bbase, const float* __restrict__ ws,
        void* __restrict__ out, const void* s6r) {
    const bool bf = detect_bf16(s6r);
    __shared__ float bins[BSZ];
    __shared__ unsigned irow[BSZ * 13];     // 13-dword stride: bank spread
    int b = blockIdx.x;
    int a0 = b << BSH;
    int na = NATOMS - a0; if (na > BSZ) na = BSZ;
    for (int t = threadIdx.x; t < BSZ; t += 512) bins[t] = 0.f;
    const unsigned* betaU = (const unsigned*)(ws + OFF_BETA);
    for (int t = threadIdx.x; t < na * 12; t += 512) {
        int l = t / 12, k = t - l * 12;
        irow[l * 13 + k] = betaU[(size_t)(a0 + l) * 12 + k];
    }
    __syncthreads();
    float s6 = ws[1], s8 = ws[2], a1 = ws[3], a2 = ws[4];
    int bs = bbase[b], be = bbase[b + 1];
    const char* B = (const char*)betaU;
    for (int p = bs + (int)threadIdx.x; p < be; p += 2*512) {
        int p2 = p + 512;
        bool h2 = (p2 < be);
        uint2 r1 = rec[p];
        uint2 r2 = h2 ? rec[p2] : r1;
        int il1 = (r1.x >> 17) & (BSZ-1), j1 = r1.x & 0x1FFFF;
        int il2 = (r2.x >> 17) & (BSZ-1), j2 = r2.x & 0x1FFFF;
        const uint4* J1 = (const uint4*)(B + (size_t)j1 * 48);
        const uint4* J2 = (const uint4*)(B + (size_t)j2 * 48);
        uint4 ja0 = J1[0], ja1 = J1[1], ja2 = J1[2];
        uint4 jb0 = J2[0], jb1 = J2[1], jb2 = J2[2];
        float vi[24], vj[24];
        #pragma unroll
        for (int k = 0; k < 12; ++k) up2(irow[il1*13 + k], vi + 2*k);
        unpack24(ja0, ja1, ja2, vj);
        float e1 = pair_energy(vi, vj, __uint_as_float(r1.y), s6, s8, a1, a2);
        atomicAdd(&bins[il1], e1);
        if (h2) {
            #pragma unroll
            for (int k = 0; k < 12; ++k) up2(irow[il2*13 + k], vi + 2*k);
            unpack24(jb0, jb1, jb2, vj);
            float e2 = pair_energy(vi, vj, __uint_as_float(r2.y), s6, s8, a1, a2);
            atomicAdd(&bins[il2], e2);
        }
    }
    __syncthreads();
    for (int t = threadIdx.x; t < na; t += 512) {
        float v = HALF_HART * bins[t];
        if (bf) ((__hip_bfloat16*)out)[a0 + t] = __float2bfloat16(v);
        else    ((float*)out)[a0 + t] = v;
    }
}

// =================== FALLBACK PATH (round-4, global atomics) =================

__global__ void k_prep_fb(const int* __restrict__ refsys, const int* __restrict__ species,
                          const void* zeff, const void* refh, const void* sscale,
                          const void* secaiw, const void* gam, const void* ascale,
                          const void* alphaiw, const void* hcount, const void* cpw,
                          const void* rcov, const void* en,
                          const void* s6r, const void* s8r, const void* a1r,
                          const void* a2r, const void* sqr,
                          float* __restrict__ ws) {
    const bool bf = detect_bf16(s6r);
    prep_body(blockIdx.x * blockDim.x + threadIdx.x, bf, refsys, species, zeff,
              refh, sscale, secaiw, gam, ascale, alphaiw, hcount, cpw, rcov, en,
              s6r, s8r, a1r, a2r, sqr, ws);
}

__device__ __forceinline__ float2 ldf2(const void* p, int t, bool bf) {
    if (bf) {
        unsigned int u = ((const unsigned int*)p)[t];
        return make_float2(__uint_as_float(u << 16),
                           __uint_as_float(u & 0xFFFF0000u));
    }
    return ((const float2*)p)[t];
}

__global__ void k_ncoord_fb(const int* __restrict__ eidx, const void* lengths,
                            const void* s6r, float* __restrict__ ws) {
    const bool bf = detect_bf16(s6r);
    int t = blockIdx.x * blockDim.x + threadIdx.x;
    if (2*t >= NPAIRS) return;
    int2 ii = ((const int2*)eidx)[t];
    int2 jj = ((const int2*)(eidx + NPAIRS))[t];
    float2 L = ldf2(lengths, t, bf);
    const float2* AD = (const float2*)(ws + OFF_AD);
    float2 ai = AD[ii.x], aj = AD[jj.x];
    float2 bi = AD[ii.y], bj = AD[jj.y];
    float r0  = L.x * INV_BOHR;
    float rc0 = (4.f/3.f) * (ai.x + aj.x);
    float d0  = fabsf(ai.y - aj.y) + CK5;
    float cf0 = CK4 * expf(-(d0*d0) * INV_K6) * 0.5f * (1.f + erff(-CKK * (r0 - rc0) / rc0));
    float r1  = L.y * INV_BOHR;
    float rc1 = (4.f/3.f) * (bi.x + bj.x);
    float d1  = fabsf(bi.y - bj.y) + CK5;
    float cf1 = CK4 * expf(-(d1*d1) * INV_K6) * 0.5f * (1.f + erff(-CKK * (r1 - rc1) / rc1));
    atomicAdd(ws + OFF_NCOORD + ii.x, cf0);
    atomicAdd(ws + OFF_NCOORD + ii.y, cf1);
}

// fallback beta: global tables (alpha is already pre-scaled by prep)
__global__ void k_beta_fb(const int* __restrict__ species, const void* pq,
                          const void* zeff, const void* gam,
                          const void* mask, const void* wght, const void* cn,
                          const void* refq, const void* sq4, const void* s6r,
                          float* __restrict__ ws) {
    const bool bf = detect_bf16(s6r);
    int k = blockIdx.x * blockDim.x + threadIdx.x;
    if (k >= NATOMS) return;
    int sp = species[k];
    float nce = ws[OFF_NCOORD + k];
    float spq = ws[0];
    float gw[NREF];
    float sum = 0.f;
    #pragma unroll
    for (int a = 0; a < NREF; ++a) {
        float g = 0.f;
        #pragma unroll
        for (int c = 0; c < NC; ++c) {
            int idx = (sp*NREF + a)*NC + c;
            float dlt = nce - ldf(cn, idx, bf);
            g += ldf(mask, idx, bf) * expf(-6.f * ldf(wght, idx, bf) * dlt * dlt);
        }
        gw[a] = g; sum += g;
    }
    float inv  = 1.f / fmaxf(sum, 1e-7f);
    float ze   = ldf(zeff, sp, bf);
    float qmod = ze + ldf(pq, k, bf);
    float gm   = ldf(gam, sp, bf);
    float beta[NW];
    #pragma unroll
    for (int w = 0; w < NW; ++w) beta[w] = 0.f;
    const float* A = ws + OFF_ALPHA + sp * (NREF*NW);
    #pragma unroll
    for (int a = 0; a < NREF; ++a) {
        float qref = ze + ldf(refq, sp*NREF + a, bf) * spq;
        float zf = (qmod > 1e-8f)
                 ? expf(3.f * (1.f - expf(2.f * gm * (1.f - qref / qmod))))
                 : E3F;
        float za = zf * gw[a] * inv;
        #pragma unroll
        for (int w = 0; w < NW; ++w) beta[w] = fmaf(A[a*NW + w], za, beta[w]);
    }
    alignas(16) __half hrow[24];
    #pragma unroll
    for (int w = 0; w < NW; ++w) hrow[w] = __float2half(beta[w]);  // alpha pre-scaled
    hrow[23] = __float2half(ldf(sq4, sp, bf));
    uint4* dst = (uint4*)((char*)(ws + OFF_BETA) + (size_t)k * 48);
    const uint4* src = (const uint4*)hrow;
    dst[0] = src[0]; dst[1] = src[1]; dst[2] = src[2];
}

__global__ void k_energy_fb(const int* __restrict__ eidx, const void* lengths,
                            const void* s6r, float* __restrict__ ws) {
    const bool bf = detect_bf16(s6r);
    int t = blockIdx.x * blockDim.x + threadIdx.x;
    if (2*t >= NPAIRS) return;
    int2 ii = ((const int2*)eidx)[t];
    int2 jj = ((const int2*)(eidx + NPAIRS))[t];
    float2 L = ldf2(lengths, t, bf);
    const char* B = (const char*)(ws + OFF_BETA);
    const uint4* qi0 = (const uint4*)(B + (size_t)ii.x * 48);
    const uint4* qj0 = (const uint4*)(B + (size_t)jj.x * 48);
    const uint4* qi1 = (const uint4*)(B + (size_t)ii.y * 48);
    const uint4* qj1 = (const uint4*)(B + (size_t)jj.y * 48);
    uint4 ra0 = qi0[0], ra1 = qi0[1], ra2 = qi0[2];
    uint4 rb0 = qj0[0], rb1 = qj0[1], rb2 = qj0[2];
    uint4 rc0 = qi1[0], rc1 = qi1[1], rc2 = qi1[2];
    uint4 rd0 = qj1[0], rd1 = qj1[1], rd2 = qj1[2];
    float s6 = ws[1], s8 = ws[2], a1 = ws[3], a2 = ws[4];
    float vi[24], vj[24];
    unpack24(ra0, ra1, ra2, vi);
    unpack24(rb0, rb1, rb2, vj);
    float e0 = pair_energy(vi, vj, L.x, s6, s8, a1, a2);
    unpack24(rc0, rc1, rc2, vi);
    unpack24(rd0, rd1, rd2, vj);
    float e1 = pair_energy(vi, vj, L.y, s6, s8, a1, a2);
    atomicAdd(ws + OFF_ENERGY + ii.x, e0);
    atomicAdd(ws + OFF_ENERGY + ii.y, e1);
}

__global__ void k_final(const float* __restrict__ ws, void* out, const void* s6r) {
    const bool bf = detect_bf16(s6r);
    int k = blockIdx.x * blockDim.x + threadIdx.x;
    if (k >= NATOMS) return;
    float v = HALF_HART * ws[OFF_ENERGY + k];
    if (bf) ((__hip_bfloat16*)out)[k] = __float2bfloat16(v);
    else    ((float*)out)[k] = v;
}

// ---- launch ------------------------------------------------------------------
extern "C" void kernel_launch(void* const* d_in, const int* in_sizes, int n_in,
                              void* d_out, int out_size, void* d_ws, size_t ws_size,
                              hipStream_t stream) {
    (void)in_sizes; (void)n_in; (void)out_size;

    const int*  species = (const int*)d_in[0];
    const int*  eidx    = (const int*)d_in[1];
    const void* lengths = d_in[2];
    const void* pq      = d_in[3];
    const void* s6r     = d_in[4];
    const void* s8r     = d_in[5];
    const void* a1r     = d_in[6];
    const void* a2r     = d_in[7];
    const void* sqr     = d_in[8];
    const int*  refsys  = (const int*)d_in[9];
    const void* zeff    = d_in[10];
    const void* refh    = d_in[11];
    const void* sscale  = d_in[12];
    const void* secaiw  = d_in[13];
    const void* gam     = d_in[14];
    const void* ascale  = d_in[15];
    const void* alphaiw = d_in[16];
    const void* hcount  = d_in[17];
    const void* cpw     = d_in[18];
    const void* rcov    = d_in[19];
    const void* en      = d_in[20];
    const void* mask    = d_in[21];
    const void* wght    = d_in[22];
    const void* cn      = d_in[23];
    const void* refq    = d_in[25];
    const void* sq4     = d_in[26];

    float* ws = (float*)d_ws;
    const bool use_sort = (ws_size >= SORT_WS_NEED);

    if (use_sort) {
        int*   hist  = (int*)(ws + OFF_HIST);
        int*   btot  = (int*)(ws + OFF_BTOT);
        int*   bbase = (int*)(ws + OFF_BBASE);
        uint2* rec   = (uint2*)(ws + OFF_REC);

        k_prep_hist  <<<PREP_BLKS + NBLK, 512, 0, stream>>>(refsys, species,
                         zeff, refh, sscale, secaiw, gam, ascale, alphaiw,
                         hcount, cpw, rcov, en, s6r, s8r, a1r, a2r, sqr,
                         eidx, hist, ws);
        k_scan_bucket<<<NB, 1024, 0, stream>>>(hist, btot);
        k_scan_base  <<<1,  1024, 0, stream>>>(btot, bbase);
        k_scatter_pack<<<NBLK + PACK_BLKS, 512, 0, stream>>>(eidx, lengths, s6r,
                         hist, bbase, rec, zeff, gam, mask, wght, cn, refq,
                         sq4, ws);
        k_ncbeta     <<<NB, 512, 0, stream>>>(rec, bbase, species, pq, s6r, ws);
        k_energy_s   <<<NB, 512, 0, stream>>>(rec, bbase, ws, d_out, s6r);
    } else {
        hipMemsetAsync(ws + OFF_NCOORD, 0, (size_t)(2 * NATOMS) * sizeof(float), stream);
        k_prep_fb  <<<(NATOMS   + 511)/512, 512, 0, stream>>>(refsys, species,
                        zeff, refh, sscale, secaiw, gam, ascale, alphaiw,
                        hcount, cpw, rcov, en, s6r, s8r, a1r, a2r, sqr, ws);
        k_ncoord_fb<<<(NPAIRS/2 + 255)/256, 256, 0, stream>>>(eidx, lengths, s6r, ws);
        k_beta_fb  <<<(NATOMS   + 255)/256, 256, 0, stream>>>(species, pq, zeff, gam,
                        mask, wght, cn, refq, sq4, s6r, ws);
        k_energy_fb<<<(NPAIRS/2 + 255)/256, 256, 0, stream>>>(eidx, lengths, s6r, ws);
        k_final    <<<(NATOMS   + 255)/256, 256, 0, stream>>>(ws, d_out, s6r);
    }
}